// Round 6
// baseline (422.170 us; speedup 1.0000x reference)
//
#include <hip/hip_runtime.h>

#define HH 128
#define WW 224
#define HW_ (HH * WW)   // 28672

typedef short short8 __attribute__((ext_vector_type(8)));
typedef float f32x4 __attribute__((ext_vector_type(4)));
typedef unsigned short ushort4v __attribute__((ext_vector_type(4)));

__device__ __forceinline__ float lrelu_f(float v) { return v >= 0.f ? v : 0.1f * v; }

__device__ __forceinline__ unsigned short f2bf(float f) {
  union { float f; unsigned u; } x; x.f = f;
  unsigned r = x.u + 0x7fff + ((x.u >> 16) & 1);   // RNE
  return (unsigned short)(r >> 16);
}
__device__ __forceinline__ float bf2f(unsigned short u) {
  union { unsigned u; float f; } x; x.u = ((unsigned)u) << 16; return x.f;
}

// ---- prep: concat(nbr,ref) -> channel-last bf16 x1t[b][p][128] ----
__global__ __launch_bounds__(256)
void prep_xt(const float* __restrict__ nbr, const float* __restrict__ ref,
             unsigned short* __restrict__ xt) {
  const int lane = threadIdx.x & 63;
  const int q = threadIdx.x >> 6;          // channel quarter (32 ch)
  const int p = blockIdx.x * 64 + lane;
  const int b = blockIdx.y;
  const int c0 = q * 32;
  const float* src = (c0 < 64) ? (nbr + ((size_t)b * 64 + c0) * HW_)
                               : (ref + ((size_t)b * 64 + (c0 - 64)) * HW_);
  unsigned short tmp[32];
  #pragma unroll
  for (int i = 0; i < 32; ++i) tmp[i] = f2bf(src[(size_t)i * HW_ + p]);
  unsigned short* dst = xt + ((size_t)b * HW_ + p) * 128 + c0;
  #pragma unroll
  for (int i = 0; i < 4; ++i)
    *(short8*)(dst + i * 8) = *(const short8*)(tmp + i * 8);
}

// ---- prep: conv weight [O][C][9] fp32 -> [9][Opad][C] bf16 (zero-pad o>=O) ----
__global__ void prep_w(const float* __restrict__ w, unsigned short* __restrict__ wt,
                       int O, int Opad, int C) {
  int idx = blockIdx.x * 256 + threadIdx.x;
  int total = Opad * C * 9;
  if (idx >= total) return;
  int c = idx % C;
  int o = (idx / C) % Opad;
  int k = idx / (C * Opad);
  float v = (o < O) ? w[((size_t)o * C + c) * 9 + k] : 0.f;
  wt[idx] = f2bf(v);
}

// ---- prep: dcn weight [O][C][9] fp32 -> bf16 [o][g*160 + k*16 + c16], K-tail zeroed ----
__global__ void prep_wdcn(const float* __restrict__ w, unsigned short* __restrict__ wt) {
  int i = blockIdx.x * 256 + threadIdx.x;   // over 64*640 = 40960
  if (i >= 64 * 640) return;
  const int o = i / 640;
  const int r = i % 640;
  const int g = r / 160;
  const int kk = r % 160;
  const int k = kk / 16;
  const int c16 = kk % 16;
  float v = (k < 9) ? w[((size_t)o * 64 + g * 16 + c16) * 9 + k] : 0.f;
  wt[i] = f2bf(v);
}

// ---- implicit-GEMM 3x3 conv via MFMA. Wave: 64 pixels x NFRAG*16 outputs ----
template<int CIN, int NFRAG, int CROW, bool LRELU>
__global__ __launch_bounds__(256)
void conv_mfma(const unsigned short* __restrict__ xt, const unsigned short* __restrict__ wt,
               const float* __restrict__ bias, unsigned short* __restrict__ out, int coutReal) {
  const int lane = threadIdx.x & 63;
  const int wave = threadIdx.x >> 6;
  const int b = blockIdx.y;
  const int m_base = blockIdx.x * 256 + wave * 64;
  const int l15 = lane & 15;
  const int lg = lane >> 4;

  int yy[4], xx[4];
  #pragma unroll
  for (int mf = 0; mf < 4; ++mf) {
    const int pp = m_base + mf * 16 + l15;
    yy[mf] = pp / WW;
    xx[mf] = pp % WW;
  }
  const unsigned short* xb = xt + (size_t)b * HW_ * CIN;

  f32x4 acc[4][NFRAG];
  #pragma unroll
  for (int mf = 0; mf < 4; ++mf)
    #pragma unroll
    for (int nf = 0; nf < NFRAG; ++nf) acc[mf][nf] = (f32x4){0.f, 0.f, 0.f, 0.f};

  #pragma unroll 3
  for (int k = 0; k < 9; ++k) {
    const int ky = k / 3 - 1, kx = k % 3 - 1;
    bool v[4];
    int q[4];
    #pragma unroll
    for (int mf = 0; mf < 4; ++mf) {
      v[mf] = ((unsigned)(yy[mf] + ky) < HH) & ((unsigned)(xx[mf] + kx) < WW);
      q[mf] = v[mf] ? (m_base + mf * 16 + l15 + ky * WW + kx) : 0;
    }
    const unsigned short* wp = wt + ((size_t)k * (NFRAG * 16) + l15) * CIN + lg * 8;
    #pragma unroll
    for (int cb = 0; cb < CIN / 32; ++cb) {
      short8 av[4];
      #pragma unroll
      for (int mf = 0; mf < 4; ++mf) {
        short8 a = *(const short8*)(xb + (size_t)q[mf] * CIN + lg * 8 + cb * 32);
        av[mf] = v[mf] ? a : (short8)0;
      }
      #pragma unroll
      for (int nf = 0; nf < NFRAG; ++nf) {
        const short8 bv = *(const short8*)(wp + (size_t)nf * 16 * CIN + cb * 32);
        #pragma unroll
        for (int mf = 0; mf < 4; ++mf)
          acc[mf][nf] = __builtin_amdgcn_mfma_f32_16x16x32_bf16(av[mf], bv, acc[mf][nf], 0, 0, 0);
      }
    }
  }

  unsigned short* ob = out + (size_t)b * HW_ * CROW;
  #pragma unroll
  for (int nf = 0; nf < NFRAG; ++nf) {
    const int o = nf * 16 + l15;
    const bool ov = (o < coutReal);
    const float bz = ov ? bias[o] : 0.f;
    #pragma unroll
    for (int mf = 0; mf < 4; ++mf) {
      #pragma unroll
      for (int r = 0; r < 4; ++r) {
        const int pix = m_base + mf * 16 + lg * 4 + r;
        float vv = acc[mf][nf][r] + bz;
        if (LRELU) vv = lrelu_f(vv);
        if (ov) ob[(size_t)pix * CROW + o] = f2bf(vv);
      }
    }
  }
}

// ---- DCN v2: barrier-free, wave-self-contained. Wave = 16 px, all 64 outputs ----
// Per group g: sample 16px x 16ch -> wave-private LDS [16][168] (K-slice 160,
// taps fill [0,144), tail [144,160) pre-zeroed, weights zero-padded to match),
// then 5 MFMA K32-steps vs weights wdt[o][g*160+...]. No __syncthreads anywhere.
#define DLROW 168
__global__ __launch_bounds__(256)
void dcn_v2(const unsigned short* __restrict__ x1t,  // [B][HW][128] bf16 (ch 0-63 = nbr)
            const unsigned short* __restrict__ offt, // [B][HW][72] bf16
            const unsigned short* __restrict__ wdt,  // [64][640] bf16
            const float* __restrict__ bias, float* __restrict__ out) {
  __shared__ __align__(16) short smp[4][16][DLROW];   // 21504 B
  const int tid = threadIdx.x;
  const int w = tid >> 6, l = tid & 63;
  const int l15 = l & 15, lg = l >> 4;
  const int b = blockIdx.y;
  const int p_img = blockIdx.x * 64 + w * 16 + l15;
  const int y = p_img / WW, x = p_img % WW;
  const unsigned short* xb = x1t + (size_t)b * HW_ * 128;

  // zero the K-tail [144,160) once (never overwritten; matches zero weights)
  *(unsigned long long*)&smp[w][l15][144 + lg * 4] = 0ULL;

  f32x4 acc[4];
  #pragma unroll
  for (int mf = 0; mf < 4; ++mf) acc[mf] = (f32x4){0.f, 0.f, 0.f, 0.f};

  const unsigned* orow = (const unsigned*)(offt + ((size_t)b * HW_ + p_img) * 72);

  #pragma unroll 1
  for (int g = 0; g < 4; ++g) {
    const int cofs = g * 16 + lg * 4;
    unsigned odr[9];
    #pragma unroll
    for (int k = 0; k < 9; ++k) odr[k] = orow[g * 9 + k];
    #pragma unroll 3
    for (int k = 0; k < 9; ++k) {
      const unsigned dpair = odr[k];
      const float dy = bf2f((unsigned short)(dpair & 0xffff));
      const float dx = bf2f((unsigned short)(dpair >> 16));
      const float sy = dy + (float)(y - 1 + k / 3);
      const float sx = dx + (float)(x - 1 + k % 3);
      const float fy = floorf(sy);
      const float fx = floorf(sx);
      const int y0 = (int)fy;
      const int x0 = (int)fx;
      const float ay = sy - fy;
      const float ax = sx - fx;
      float w00 = (1.f - ay) * (1.f - ax);
      float w01 = (1.f - ay) * ax;
      float w10 = ay * (1.f - ax);
      float w11 = ay * ax;
      const bool vy0 = (y0 >= 0) & (y0 < HH);
      const bool vy1 = (y0 + 1 >= 0) & (y0 + 1 < HH);
      const bool vx0 = (x0 >= 0) & (x0 < WW);
      const bool vx1 = (x0 + 1 >= 0) & (x0 + 1 < WW);
      w00 = (vy0 & vx0) ? w00 : 0.f;
      w01 = (vy0 & vx1) ? w01 : 0.f;
      w10 = (vy1 & vx0) ? w10 : 0.f;
      w11 = (vy1 & vx1) ? w11 : 0.f;
      const int cy0 = min(max(y0, 0), HH - 1);
      const int cy1 = min(max(y0 + 1, 0), HH - 1);
      const int cx0 = min(max(x0, 0), WW - 1);
      const int cx1 = min(max(x0 + 1, 0), WW - 1);
      const ushort4v q00 = *(const ushort4v*)(xb + ((size_t)(cy0 * WW + cx0)) * 128 + cofs);
      const ushort4v q01 = *(const ushort4v*)(xb + ((size_t)(cy0 * WW + cx1)) * 128 + cofs);
      const ushort4v q10 = *(const ushort4v*)(xb + ((size_t)(cy1 * WW + cx0)) * 128 + cofs);
      const ushort4v q11 = *(const ushort4v*)(xb + ((size_t)(cy1 * WW + cx1)) * 128 + cofs);
      unsigned short sv[4];
      #pragma unroll
      for (int j = 0; j < 4; ++j) {
        const float s = w00 * bf2f(q00[j]) + w01 * bf2f(q01[j])
                      + w10 * bf2f(q10[j]) + w11 * bf2f(q11[j]);
        sv[j] = f2bf(s);
      }
      *(unsigned long long*)&smp[w][l15][k * 16 + lg * 4] = *(const unsigned long long*)sv;
    }
    // GEMM slice for this group: K = 160 (5 x K32), same-wave LDS (no barrier)
    #pragma unroll
    for (int kb = 0; kb < 5; ++kb) {
      const short8 pf = *(const short8*)&smp[w][l15][kb * 32 + lg * 8];
      #pragma unroll
      for (int mf = 0; mf < 4; ++mf) {
        const short8 wf = *(const short8*)(wdt + (size_t)(mf * 16 + l15) * 640
                                           + g * 160 + kb * 32 + lg * 8);
        acc[mf] = __builtin_amdgcn_mfma_f32_16x16x32_bf16(wf, pf, acc[mf], 0, 0, 0);
      }
    }
  }

  // D: col(l15)=px, row=o -> coalesced px stores
  float* ob = out + (size_t)b * 64 * HW_;
  #pragma unroll
  for (int mf = 0; mf < 4; ++mf) {
    #pragma unroll
    for (int r = 0; r < 4; ++r) {
      const int o = mf * 16 + lg * 4 + r;
      ob[(size_t)o * HW_ + p_img] = lrelu_f(acc[mf][r] + bias[o]);
    }
  }
}

extern "C" void kernel_launch(void* const* d_in, const int* in_sizes, int n_in,
                              void* d_out, int out_size, void* d_ws, size_t ws_size,
                              hipStream_t stream) {
  const float* nbr   = (const float*)d_in[0];
  const float* ref   = (const float*)d_in[1];
  const float* w_co1 = (const float*)d_in[2];
  const float* b_co1 = (const float*)d_in[3];
  const float* w_m1  = (const float*)d_in[4];
  const float* b_m1  = (const float*)d_in[5];
  const float* w_m2  = (const float*)d_in[6];
  const float* b_m2  = (const float*)d_in[7];
  const float* w_m3  = (const float*)d_in[8];
  const float* b_m3  = (const float*)d_in[9];
  const float* w_dcn = (const float*)d_in[10];
  const float* b_dcn = (const float*)d_in[11];
  float* out = (float*)d_out;

  char* ws = (char*)d_ws;
  // x1t [B][HW][128] bf16: [0, 29.36M)            -- persistent (dcn samples it)
  // featt: [29.36M, 44.04M)  -> later m2t aliases it
  // m1t:   [44.04M, 58.72M)  -> later offt aliases it (offt = 16.5MB, to 60.55M)
  // weights at 60.56M
  unsigned short* x1t   = (unsigned short*)(ws);
  unsigned short* featt = (unsigned short*)(ws + 29360128);
  unsigned short* m1t   = (unsigned short*)(ws + 44040192);
  unsigned short* m2t   = (unsigned short*)(ws + 29360128);   // alias featt
  unsigned short* offt  = (unsigned short*)(ws + 44040192);   // alias m1t (16.5MB)
  char* wbase = ws + 60555264;
  unsigned short* wt1  = (unsigned short*)(wbase);            // 147456
  unsigned short* wtm1 = (unsigned short*)(wbase + 147456);   // 73728
  unsigned short* wtm2 = (unsigned short*)(wbase + 221184);   // 73728
  unsigned short* wtm3 = (unsigned short*)(wbase + 294912);   // 92160
  unsigned short* wdt  = (unsigned short*)(wbase + 387072);   // 64*640*2 = 81920

  dim3 blk(256);
  prep_w<<<dim3(288), blk, 0, stream>>>(w_co1, wt1, 64, 64, 128);
  prep_w<<<dim3(144), blk, 0, stream>>>(w_m1, wtm1, 64, 64, 64);
  prep_w<<<dim3(144), blk, 0, stream>>>(w_m2, wtm2, 64, 64, 64);
  prep_w<<<dim3(180), blk, 0, stream>>>(w_m3, wtm3, 72, 80, 64);
  prep_wdcn<<<dim3(160), blk, 0, stream>>>(w_dcn, wdt);
  prep_xt<<<dim3(448, 4), blk, 0, stream>>>(nbr, ref, x1t);
  conv_mfma<128, 4, 64, true ><<<dim3(112, 4), blk, 0, stream>>>(x1t,   wt1,  b_co1, featt, 64);
  conv_mfma< 64, 4, 64, true ><<<dim3(112, 4), blk, 0, stream>>>(featt, wtm1, b_m1,  m1t,   64);
  conv_mfma< 64, 4, 64, true ><<<dim3(112, 4), blk, 0, stream>>>(m1t,   wtm2, b_m2,  m2t,   64);
  conv_mfma< 64, 5, 72, false><<<dim3(112, 4), blk, 0, stream>>>(m2t,   wtm3, b_m3,  offt,  72);
  dcn_v2<<<dim3(448, 4), blk, 0, stream>>>(x1t, offt, wdt, b_dcn, out);
}

// Round 7
// 413.229 us; speedup vs baseline: 1.0216x; 1.0216x over previous
//
#include <hip/hip_runtime.h>

#define HH 128
#define WW 224
#define HW_ (HH * WW)   // 28672

typedef short short8 __attribute__((ext_vector_type(8)));
typedef float f32x4 __attribute__((ext_vector_type(4)));
typedef unsigned short ushort4v __attribute__((ext_vector_type(4)));

__device__ __forceinline__ float lrelu_f(float v) { return v >= 0.f ? v : 0.1f * v; }

__device__ __forceinline__ unsigned short f2bf(float f) {
  union { float f; unsigned u; } x; x.f = f;
  unsigned r = x.u + 0x7fff + ((x.u >> 16) & 1);   // RNE
  return (unsigned short)(r >> 16);
}
__device__ __forceinline__ float bf2f(unsigned short u) {
  union { unsigned u; float f; } x; x.u = ((unsigned)u) << 16; return x.f;
}

// ---- prep: concat(nbr,ref) -> channel-last bf16 x1t[b][p][128] ----
__global__ __launch_bounds__(256)
void prep_xt(const float* __restrict__ nbr, const float* __restrict__ ref,
             unsigned short* __restrict__ xt) {
  const int lane = threadIdx.x & 63;
  const int q = threadIdx.x >> 6;          // channel quarter (32 ch)
  const int p = blockIdx.x * 64 + lane;
  const int b = blockIdx.y;
  const int c0 = q * 32;
  const float* src = (c0 < 64) ? (nbr + ((size_t)b * 64 + c0) * HW_)
                               : (ref + ((size_t)b * 64 + (c0 - 64)) * HW_);
  unsigned short tmp[32];
  #pragma unroll
  for (int i = 0; i < 32; ++i) tmp[i] = f2bf(src[(size_t)i * HW_ + p]);
  unsigned short* dst = xt + ((size_t)b * HW_ + p) * 128 + c0;
  #pragma unroll
  for (int i = 0; i < 4; ++i)
    *(short8*)(dst + i * 8) = *(const short8*)(tmp + i * 8);
}

// ---- prep: conv weight [O][C][9] fp32 -> [9][Opad][C] bf16 (zero-pad o>=O) ----
__global__ void prep_w(const float* __restrict__ w, unsigned short* __restrict__ wt,
                       int O, int Opad, int C) {
  int idx = blockIdx.x * 256 + threadIdx.x;
  int total = Opad * C * 9;
  if (idx >= total) return;
  int c = idx % C;
  int o = (idx / C) % Opad;
  int k = idx / (C * Opad);
  float v = (o < O) ? w[((size_t)o * C + c) * 9 + k] : 0.f;
  wt[idx] = f2bf(v);
}

// ---- prep: dcn weight [O][C][9] fp32 -> bf16 [o][g*144 + k*16 + c16] ----
__global__ void prep_wdcn(const float* __restrict__ w, unsigned short* __restrict__ wt) {
  int i = blockIdx.x * 256 + threadIdx.x;   // over 64*576 = 36864
  if (i >= 64 * 576) return;
  const int o = i / 576;
  const int r = i % 576;
  const int g = r / 144;
  const int k = (r % 144) / 16;
  const int c16 = r % 16;
  wt[i] = f2bf(w[((size_t)o * 64 + g * 16 + c16) * 9 + k]);
}

// ---- implicit-GEMM 3x3 conv via MFMA. Wave: 64 pixels x NFRAG*16 outputs ----
template<int CIN, int NFRAG, int CROW, bool LRELU>
__global__ __launch_bounds__(256, 3)
void conv_mfma(const unsigned short* __restrict__ xt, const unsigned short* __restrict__ wt,
               const float* __restrict__ bias, unsigned short* __restrict__ out, int coutReal) {
  const int lane = threadIdx.x & 63;
  const int wave = threadIdx.x >> 6;
  const int b = blockIdx.y;
  const int m_base = blockIdx.x * 256 + wave * 64;
  const int l15 = lane & 15;
  const int lg = lane >> 4;

  int yy[4], xx[4];
  #pragma unroll
  for (int mf = 0; mf < 4; ++mf) {
    const int pp = m_base + mf * 16 + l15;
    yy[mf] = pp / WW;
    xx[mf] = pp % WW;
  }
  const unsigned short* xb = xt + (size_t)b * HW_ * CIN;

  f32x4 acc[4][NFRAG];
  #pragma unroll
  for (int mf = 0; mf < 4; ++mf)
    #pragma unroll
    for (int nf = 0; nf < NFRAG; ++nf) acc[mf][nf] = (f32x4){0.f, 0.f, 0.f, 0.f};

  #pragma unroll 2
  for (int k = 0; k < 9; ++k) {
    const int ky = k / 3 - 1, kx = k % 3 - 1;
    bool v[4];
    int q[4];
    #pragma unroll
    for (int mf = 0; mf < 4; ++mf) {
      v[mf] = ((unsigned)(yy[mf] + ky) < HH) & ((unsigned)(xx[mf] + kx) < WW);
      q[mf] = v[mf] ? (m_base + mf * 16 + l15 + ky * WW + kx) : 0;
    }
    const unsigned short* wp = wt + ((size_t)k * (NFRAG * 16) + l15) * CIN + lg * 8;
    #pragma unroll
    for (int cb = 0; cb < CIN / 32; ++cb) {
      short8 av[4];
      #pragma unroll
      for (int mf = 0; mf < 4; ++mf) {
        short8 a = *(const short8*)(xb + (size_t)q[mf] * CIN + lg * 8 + cb * 32);
        av[mf] = v[mf] ? a : (short8)0;
      }
      #pragma unroll
      for (int nf = 0; nf < NFRAG; ++nf) {
        const short8 bv = *(const short8*)(wp + (size_t)nf * 16 * CIN + cb * 32);
        #pragma unroll
        for (int mf = 0; mf < 4; ++mf)
          acc[mf][nf] = __builtin_amdgcn_mfma_f32_16x16x32_bf16(av[mf], bv, acc[mf][nf], 0, 0, 0);
      }
    }
  }

  unsigned short* ob = out + (size_t)b * HW_ * CROW;
  #pragma unroll
  for (int nf = 0; nf < NFRAG; ++nf) {
    const int o = nf * 16 + l15;
    const bool ov = (o < coutReal);
    const float bz = ov ? bias[o] : 0.f;
    #pragma unroll
    for (int mf = 0; mf < 4; ++mf) {
      #pragma unroll
      for (int r = 0; r < 4; ++r) {
        const int pix = m_base + mf * 16 + lg * 4 + r;
        float vv = acc[mf][nf][r] + bz;
        if (LRELU) vv = lrelu_f(vv);
        if (ov) ob[(size_t)pix * CROW + o] = f2bf(vv);
      }
    }
  }
}

// ---- DCN v3: barrier-free wave-owned, k-outer/g-inner sampling (fetch locality),
// full K=576 in wave-private LDS, then 18-step MFMA GEMM. Block = 2 waves. ----
#define DRS 580   // shorts per pixel row (1160 B; data = 1152 B)
__global__ __launch_bounds__(128)
void dcn_v3(const unsigned short* __restrict__ x1t,  // [B][HW][128] bf16 (ch 0-63 = nbr)
            const unsigned short* __restrict__ offt, // [B][HW][72] bf16
            const unsigned short* __restrict__ wdt,  // [64][576] bf16
            const float* __restrict__ bias, float* __restrict__ out) {
  __shared__ __align__(16) short smp[2][16][DRS];   // 37120 B
  const int tid = threadIdx.x;
  const int w = tid >> 6, l = tid & 63;
  const int l15 = l & 15, lg = l >> 4;
  const int b = blockIdx.y;
  const int p_img = blockIdx.x * 32 + w * 16 + l15;
  const int y = p_img / WW, x = p_img % WW;
  const unsigned short* xb = x1t + (size_t)b * HW_ * 128;
  char* myrow = (char*)&smp[w][l15][0];

  // preload all 36 offset dwords (9 x uint4, static-indexed after unroll)
  const uint4* orow = (const uint4*)(offt + ((size_t)b * HW_ + p_img) * 72);
  uint4 oq[9];
  #pragma unroll
  for (int i = 0; i < 9; ++i) oq[i] = orow[i];
  const unsigned* od32 = (const unsigned*)oq;

  // ---- sampling: taps outer, groups inner (adjacent 4-group loads share lines) ----
  #pragma unroll 3
  for (int k = 0; k < 9; ++k) {
    const int py = y - 1 + k / 3;
    const int pxx = x - 1 + k % 3;
    #pragma unroll
    for (int g = 0; g < 4; ++g) {
      const unsigned dpair = od32[g * 9 + k];
      const float dy = bf2f((unsigned short)(dpair & 0xffff));
      const float dx = bf2f((unsigned short)(dpair >> 16));
      const float sy = dy + (float)py;
      const float sx = dx + (float)pxx;
      const float fy = floorf(sy);
      const float fx = floorf(sx);
      const int y0 = (int)fy;
      const int x0 = (int)fx;
      const float ay = sy - fy;
      const float ax = sx - fx;
      float w00 = (1.f - ay) * (1.f - ax);
      float w01 = (1.f - ay) * ax;
      float w10 = ay * (1.f - ax);
      float w11 = ay * ax;
      const bool vy0 = (y0 >= 0) & (y0 < HH);
      const bool vy1 = (y0 + 1 >= 0) & (y0 + 1 < HH);
      const bool vx0 = (x0 >= 0) & (x0 < WW);
      const bool vx1 = (x0 + 1 >= 0) & (x0 + 1 < WW);
      w00 = (vy0 & vx0) ? w00 : 0.f;
      w01 = (vy0 & vx1) ? w01 : 0.f;
      w10 = (vy1 & vx0) ? w10 : 0.f;
      w11 = (vy1 & vx1) ? w11 : 0.f;
      const int cy0 = min(max(y0, 0), HH - 1);
      const int cy1 = min(max(y0 + 1, 0), HH - 1);
      const int cx0 = min(max(x0, 0), WW - 1);
      const int cx1 = min(max(x0 + 1, 0), WW - 1);
      const int cofs = g * 16 + lg * 4;
      const ushort4v q00 = *(const ushort4v*)(xb + ((size_t)(cy0 * WW + cx0)) * 128 + cofs);
      const ushort4v q01 = *(const ushort4v*)(xb + ((size_t)(cy0 * WW + cx1)) * 128 + cofs);
      const ushort4v q10 = *(const ushort4v*)(xb + ((size_t)(cy1 * WW + cx0)) * 128 + cofs);
      const ushort4v q11 = *(const ushort4v*)(xb + ((size_t)(cy1 * WW + cx1)) * 128 + cofs);
      unsigned short sv[4];
      #pragma unroll
      for (int j = 0; j < 4; ++j) {
        const float s = w00 * bf2f(q00[j]) + w01 * bf2f(q01[j])
                      + w10 * bf2f(q10[j]) + w11 * bf2f(q11[j]);
        sv[j] = f2bf(s);
      }
      // K index = g*144 + k*16 + lg*4 shorts -> byte g*288 + k*32 + lg*8, XOR-swizzled
      const int byte = g * 288 + k * 32 + lg * 8;
      const int sw = byte ^ ((l15 & 7) << 4);
      *(unsigned long long*)(myrow + sw) = *(const unsigned long long*)sv;
    }
  }

  // ---- GEMM: K = 576 = 18 x K32 steps, same-wave LDS (no barrier) ----
  f32x4 acc[4];
  #pragma unroll
  for (int mf = 0; mf < 4; ++mf) acc[mf] = (f32x4){0.f, 0.f, 0.f, 0.f};
  #pragma unroll
  for (int s = 0; s < 18; ++s) {
    const int byte = s * 64 + lg * 16;
    const int sw = byte ^ ((l15 & 7) << 4);
    const short8 pf = *(const short8*)(myrow + sw);
    #pragma unroll
    for (int mf = 0; mf < 4; ++mf) {
      const short8 wf = *(const short8*)(wdt + (size_t)(mf * 16 + l15) * 576 + s * 32 + lg * 8);
      acc[mf] = __builtin_amdgcn_mfma_f32_16x16x32_bf16(wf, pf, acc[mf], 0, 0, 0);
    }
  }

  // D: col(l15)=px, rows = o -> coalesced px stores
  float* ob = out + (size_t)b * 64 * HW_;
  #pragma unroll
  for (int mf = 0; mf < 4; ++mf) {
    #pragma unroll
    for (int r = 0; r < 4; ++r) {
      const int o = mf * 16 + lg * 4 + r;
      ob[(size_t)o * HW_ + p_img] = lrelu_f(acc[mf][r] + bias[o]);
    }
  }
}

extern "C" void kernel_launch(void* const* d_in, const int* in_sizes, int n_in,
                              void* d_out, int out_size, void* d_ws, size_t ws_size,
                              hipStream_t stream) {
  const float* nbr   = (const float*)d_in[0];
  const float* ref   = (const float*)d_in[1];
  const float* w_co1 = (const float*)d_in[2];
  const float* b_co1 = (const float*)d_in[3];
  const float* w_m1  = (const float*)d_in[4];
  const float* b_m1  = (const float*)d_in[5];
  const float* w_m2  = (const float*)d_in[6];
  const float* b_m2  = (const float*)d_in[7];
  const float* w_m3  = (const float*)d_in[8];
  const float* b_m3  = (const float*)d_in[9];
  const float* w_dcn = (const float*)d_in[10];
  const float* b_dcn = (const float*)d_in[11];
  float* out = (float*)d_out;

  char* ws = (char*)d_ws;
  // x1t [B][HW][128] bf16: [0, 29.36M)            -- persistent (dcn samples it)
  // featt: [29.36M, 44.04M)  -> later m2t aliases it
  // m1t:   [44.04M, 58.72M)  -> later offt aliases it (offt 16.5MB, to 60.55M)
  unsigned short* x1t   = (unsigned short*)(ws);
  unsigned short* featt = (unsigned short*)(ws + 29360128);
  unsigned short* m1t   = (unsigned short*)(ws + 44040192);
  unsigned short* m2t   = (unsigned short*)(ws + 29360128);   // alias featt
  unsigned short* offt  = (unsigned short*)(ws + 44040192);   // alias m1t (16.5MB)
  char* wbase = ws + 60555264;
  unsigned short* wt1  = (unsigned short*)(wbase);            // 147456
  unsigned short* wtm1 = (unsigned short*)(wbase + 147456);   // 73728
  unsigned short* wtm2 = (unsigned short*)(wbase + 221184);   // 73728
  unsigned short* wtm3 = (unsigned short*)(wbase + 294912);   // 92160
  unsigned short* wdt  = (unsigned short*)(wbase + 387072);   // 64*576*2 = 73728

  dim3 blk(256);
  prep_w<<<dim3(288), blk, 0, stream>>>(w_co1, wt1, 64, 64, 128);
  prep_w<<<dim3(144), blk, 0, stream>>>(w_m1, wtm1, 64, 64, 64);
  prep_w<<<dim3(144), blk, 0, stream>>>(w_m2, wtm2, 64, 64, 64);
  prep_w<<<dim3(180), blk, 0, stream>>>(w_m3, wtm3, 72, 80, 64);
  prep_wdcn<<<dim3(144), blk, 0, stream>>>(w_dcn, wdt);
  prep_xt<<<dim3(448, 4), blk, 0, stream>>>(nbr, ref, x1t);
  conv_mfma<128, 4, 64, true ><<<dim3(112, 4), blk, 0, stream>>>(x1t,   wt1,  b_co1, featt, 64);
  conv_mfma< 64, 4, 64, true ><<<dim3(112, 4), blk, 0, stream>>>(featt, wtm1, b_m1,  m1t,   64);
  conv_mfma< 64, 4, 64, true ><<<dim3(112, 4), blk, 0, stream>>>(m1t,   wtm2, b_m2,  m2t,   64);
  conv_mfma< 64, 5, 72, false><<<dim3(112, 4), blk, 0, stream>>>(m2t,   wtm3, b_m3,  offt,  72);
  dcn_v3<<<dim3(896, 4), dim3(128), 0, stream>>>(x1t, offt, wdt, b_dcn, out);
}

// Round 8
// 258.581 us; speedup vs baseline: 1.6326x; 1.5981x over previous
//
#include <hip/hip_runtime.h>

#define HH 128
#define WW 224
#define HW_ (HH * WW)   // 28672

typedef short short8 __attribute__((ext_vector_type(8)));
typedef float f32x4 __attribute__((ext_vector_type(4)));

__device__ __forceinline__ float lrelu_f(float v) { return v >= 0.f ? v : 0.1f * v; }

__device__ __forceinline__ unsigned short f2bf(float f) {
  union { float f; unsigned u; } x; x.f = f;
  unsigned r = x.u + 0x7fff + ((x.u >> 16) & 1);   // RNE
  return (unsigned short)(r >> 16);
}
__device__ __forceinline__ float bf2f(unsigned short u) {
  union { unsigned u; float f; } x; x.u = ((unsigned)u) << 16; return x.f;
}

// ---- prep: concat(nbr,ref) -> x1t[b][p][128] bf16; also xnb[b][p][64] (nbr only) ----
__global__ __launch_bounds__(256)
void prep_xt(const float* __restrict__ nbr, const float* __restrict__ ref,
             unsigned short* __restrict__ xt, unsigned short* __restrict__ xnb) {
  const int lane = threadIdx.x & 63;
  const int q = threadIdx.x >> 6;          // channel quarter (32 ch)
  const int p = blockIdx.x * 64 + lane;
  const int b = blockIdx.y;
  const int c0 = q * 32;
  const float* src = (c0 < 64) ? (nbr + ((size_t)b * 64 + c0) * HW_)
                               : (ref + ((size_t)b * 64 + (c0 - 64)) * HW_);
  unsigned short tmp[32];
  #pragma unroll
  for (int i = 0; i < 32; ++i) tmp[i] = f2bf(src[(size_t)i * HW_ + p]);
  unsigned short* dst = xt + ((size_t)b * HW_ + p) * 128 + c0;
  #pragma unroll
  for (int i = 0; i < 4; ++i)
    *(short8*)(dst + i * 8) = *(const short8*)(tmp + i * 8);
  if (c0 < 64) {
    unsigned short* dst2 = xnb + ((size_t)b * HW_ + p) * 64 + c0;
    #pragma unroll
    for (int i = 0; i < 4; ++i)
      *(short8*)(dst2 + i * 8) = *(const short8*)(tmp + i * 8);
  }
}

// ---- prep: conv weight [O][C][9] fp32 -> fragment-ordered bf16
//      wt[((k*CB + cb)*NFT + nfg)*512 + lane*8 + j], o = nfg*16+(lane&15),
//      c = cb*32+(lane>>4)*8+j ----
__global__ void prep_wfrag(const float* __restrict__ w, unsigned short* __restrict__ wt,
                           int O, int C, int NFT) {
  const int i = blockIdx.x * 256 + threadIdx.x;
  const int CB = C / 32;
  const int total = 9 * CB * NFT * 512;
  if (i >= total) return;
  const int j = i & 7;
  const int lane = (i >> 3) & 63;
  const int fid = i >> 9;
  const int nfg = fid % NFT;
  const int kcb = fid / NFT;
  const int cb = kcb % CB;
  const int k = kcb / CB;
  const int o = nfg * 16 + (lane & 15);
  const int c = cb * 32 + (lane >> 4) * 8 + j;
  float v = (o < O) ? w[((size_t)o * C + c) * 9 + k] : 0.f;
  wt[i] = f2bf(v);
}

// ---- prep: dcn weight [O=64][C=64][9] -> fragment-ordered, K padded to 160/group
//      wt[((g*5+s)*4+mf)*512 + lane*8 + j]: o=mf*16+l15, t=2s+(lg>>1), c=g*16+(lg&1)*8+j ----
__global__ void prep_wdcnf(const float* __restrict__ w, unsigned short* __restrict__ wt) {
  const int i = blockIdx.x * 256 + threadIdx.x;   // 40960
  if (i >= 40960) return;
  const int j = i & 7;
  const int lane = (i >> 3) & 63;
  const int fid = i >> 9;
  const int mf = fid & 3;
  const int s = (fid >> 2) % 5;
  const int g = fid / 20;
  const int l15 = lane & 15, lg = lane >> 4;
  const int o = mf * 16 + l15;
  const int t = 2 * s + (lg >> 1);
  const int c = g * 16 + (lg & 1) * 8 + j;
  float v = (t < 9) ? w[((size_t)o * 64 + c) * 9 + t] : 0.f;
  wt[i] = f2bf(v);
}

// ---- conv1: global-direct implicit GEMM (CIN=128), fragment-ordered weights ----
template<int CIN, int NFRAG, int CROW, bool LRELU>
__global__ __launch_bounds__(256, 3)
void conv_mfma(const unsigned short* __restrict__ xt, const unsigned short* __restrict__ wt,
               const float* __restrict__ bias, unsigned short* __restrict__ out, int coutReal) {
  const int lane = threadIdx.x & 63;
  const int wave = threadIdx.x >> 6;
  const int b = blockIdx.y;
  const int m_base = blockIdx.x * 256 + wave * 64;
  const int l15 = lane & 15;
  const int lg = lane >> 4;
  const int CB = CIN / 32;

  int yy[4], xx[4];
  #pragma unroll
  for (int mf = 0; mf < 4; ++mf) {
    const int pp = m_base + mf * 16 + l15;
    yy[mf] = pp / WW;
    xx[mf] = pp % WW;
  }
  const unsigned short* xb = xt + (size_t)b * HW_ * CIN;

  f32x4 acc[4][NFRAG];
  #pragma unroll
  for (int mf = 0; mf < 4; ++mf)
    #pragma unroll
    for (int nf = 0; nf < NFRAG; ++nf) acc[mf][nf] = (f32x4){0.f, 0.f, 0.f, 0.f};

  #pragma unroll 2
  for (int k = 0; k < 9; ++k) {
    const int ky = k / 3 - 1, kx = k % 3 - 1;
    bool v[4];
    int q[4];
    #pragma unroll
    for (int mf = 0; mf < 4; ++mf) {
      v[mf] = ((unsigned)(yy[mf] + ky) < HH) & ((unsigned)(xx[mf] + kx) < WW);
      q[mf] = v[mf] ? (m_base + mf * 16 + l15 + ky * WW + kx) : 0;
    }
    #pragma unroll
    for (int cb = 0; cb < CB; ++cb) {
      short8 av[4];
      #pragma unroll
      for (int mf = 0; mf < 4; ++mf) {
        short8 a = *(const short8*)(xb + (size_t)q[mf] * CIN + lg * 8 + cb * 32);
        av[mf] = v[mf] ? a : (short8)0;
      }
      #pragma unroll
      for (int nf = 0; nf < NFRAG; ++nf) {
        const short8 bv = *(const short8*)(wt + ((size_t)((k * CB + cb) * NFRAG + nf)) * 512 + lane * 8);
        #pragma unroll
        for (int mf = 0; mf < 4; ++mf)
          acc[mf][nf] = __builtin_amdgcn_mfma_f32_16x16x32_bf16(av[mf], bv, acc[mf][nf], 0, 0, 0);
      }
    }
  }

  unsigned short* ob = out + (size_t)b * HW_ * CROW;
  #pragma unroll
  for (int nf = 0; nf < NFRAG; ++nf) {
    const int o = nf * 16 + l15;
    const bool ov = (o < coutReal);
    const float bz = ov ? bias[o] : 0.f;
    #pragma unroll
    for (int mf = 0; mf < 4; ++mf) {
      #pragma unroll
      for (int r = 0; r < 4; ++r) {
        const int pix = m_base + mf * 16 + lg * 4 + r;
        float vv = acc[mf][nf][r] + bz;
        if (LRELU) vv = lrelu_f(vv);
        if (ov) ob[(size_t)pix * CROW + o] = f2bf(vv);
      }
    }
  }
}

// ---- conv (CIN=64) with LDS-staged 8x32 tile + 1px halo (10x34 rows, swizzled) ----
// Block: 256 thr = 4 waves; wave = rows {2w,2w+1} x 32 cols = 64 px; o-split via blockIdx.z.
template<int NFRAG, int NFT, int CROW, bool LRELU>
__global__ __launch_bounds__(256, 3)
void conv_lds(const unsigned short* __restrict__ xt, const unsigned short* __restrict__ wfrag,
              const float* __restrict__ bias, unsigned short* __restrict__ out, int coutReal) {
  __shared__ __align__(16) char xs[10 * 34 * 128];   // 43520 B
  const int tid = threadIdx.x;
  const int lane = tid & 63, wv = tid >> 6;
  const int l15 = lane & 15, lg = lane >> 4;
  const int b = blockIdx.y;
  const int ty = (blockIdx.x / 7) * 8, tx = (blockIdx.x % 7) * 32;
  const int oz = blockIdx.z;
  const unsigned short* xb = xt + (size_t)b * HW_ * 64;

  // stage halo tile: 340 px rows x 128 B, coalesced, zero-fill OOB, XOR-swizzled
  for (int ci = tid; ci < 2720; ci += 256) {
    const int ch = ci & 7;
    const int hp = ci >> 3;
    const int hr = hp / 34, hc = hp % 34;
    const int gy = ty + hr - 1, gx = tx + hc - 1;
    short8 v = (short8)0;
    if (((unsigned)gy < HH) & ((unsigned)gx < WW))
      v = *(const short8*)(xb + (size_t)(gy * WW + gx) * 64 + ch * 8);
    *(short8*)(xs + hp * 128 + ((ch * 16) ^ ((hc & 7) << 4))) = v;
  }
  __syncthreads();

  f32x4 acc[4][NFRAG];
  #pragma unroll
  for (int mf = 0; mf < 4; ++mf)
    #pragma unroll
    for (int nf = 0; nf < NFRAG; ++nf) acc[mf][nf] = (f32x4){0.f, 0.f, 0.f, 0.f};

  #pragma unroll 2
  for (int k = 0; k < 9; ++k) {
    const int ky = k / 3, kx = k % 3;   // halo offset +1 already folded in
    #pragma unroll
    for (int cb = 0; cb < 2; ++cb) {
      short8 av[4];
      #pragma unroll
      for (int mf = 0; mf < 4; ++mf) {
        const int hr = 2 * wv + (mf >> 1) + ky;
        const int hc = (mf & 1) * 16 + l15 + kx;
        av[mf] = *(const short8*)(xs + (hr * 34 + hc) * 128
                                  + ((cb * 64 + lg * 16) ^ ((hc & 7) << 4)));
      }
      #pragma unroll
      for (int nf = 0; nf < NFRAG; ++nf) {
        const short8 bv = *(const short8*)(wfrag
            + ((size_t)((k * 2 + cb) * NFT + oz * NFRAG + nf)) * 512 + lane * 8);
        #pragma unroll
        for (int mf = 0; mf < 4; ++mf)
          acc[mf][nf] = __builtin_amdgcn_mfma_f32_16x16x32_bf16(av[mf], bv, acc[mf][nf], 0, 0, 0);
      }
    }
  }

  unsigned short* ob = out + (size_t)b * HW_ * CROW;
  #pragma unroll
  for (int nf = 0; nf < NFRAG; ++nf) {
    const int o = (oz * NFRAG + nf) * 16 + l15;
    const bool ov = (o < coutReal);
    const float bz = ov ? bias[o] : 0.f;
    #pragma unroll
    for (int mf = 0; mf < 4; ++mf) {
      const int rr = ty + 2 * wv + (mf >> 1);
      #pragma unroll
      for (int r = 0; r < 4; ++r) {
        const int cc = tx + (mf & 1) * 16 + lg * 4 + r;
        float vv = acc[mf][nf][r] + bz;
        if (LRELU) vv = lrelu_f(vv);
        if (ov) ob[(size_t)(rr * WW + cc) * CROW + o] = f2bf(vv);
      }
    }
  }
}

// ---- DCN v4: register-direct. Wave = 16 px x 64 o; lane (l15,lg) samples its own
// B-fragment (tap 2s+(lg>>1), 8 ch (lg&1)*8 of group g) from xnb (128B rows). No LDS. ----
__global__ __launch_bounds__(256, 3)
void dcn_v4(const unsigned short* __restrict__ xnb,  // [B][HW][64] bf16
            const unsigned short* __restrict__ offt, // [B][HW][72] bf16
            const unsigned short* __restrict__ wdf,  // fragment-ordered [80 fids][512]
            const float* __restrict__ bias, float* __restrict__ out) {
  const int tid = threadIdx.x;
  const int w = tid >> 6, l = tid & 63;
  const int l15 = l & 15, lg = l >> 4;
  const int b = blockIdx.y;
  const int p_img = blockIdx.x * 64 + w * 16 + l15;
  const int y = p_img / WW, x = p_img % WW;
  const unsigned short* xb = xnb + (size_t)b * HW_ * 64;
  const unsigned* od = (const unsigned*)(offt + ((size_t)b * HW_ + p_img) * 72);
  const int thalf = lg >> 1;
  const int cofs0 = (lg & 1) * 8;

  f32x4 acc[4];
  #pragma unroll
  for (int mf = 0; mf < 4; ++mf) acc[mf] = (f32x4){0.f, 0.f, 0.f, 0.f};

  #pragma unroll 1
  for (int g = 0; g < 4; ++g) {
    const int cofs = g * 16 + cofs0;
    #pragma unroll 2
    for (int s = 0; s < 5; ++s) {
      const int t = 2 * s + thalf;
      short8 pf = (short8)0;
      if (t < 9) {
        const unsigned dpair = od[g * 9 + t];
        const float dy = bf2f((unsigned short)(dpair & 0xffff));
        const float dx = bf2f((unsigned short)(dpair >> 16));
        const float sy = dy + (float)(y - 1 + t / 3);
        const float sx = dx + (float)(x - 1 + t % 3);
        const float fy = floorf(sy);
        const float fx = floorf(sx);
        const int y0 = (int)fy;
        const int x0 = (int)fx;
        const float ay = sy - fy;
        const float ax = sx - fx;
        float w00 = (1.f - ay) * (1.f - ax);
        float w01 = (1.f - ay) * ax;
        float w10 = ay * (1.f - ax);
        float w11 = ay * ax;
        const bool vy0 = (y0 >= 0) & (y0 < HH);
        const bool vy1 = (y0 + 1 >= 0) & (y0 + 1 < HH);
        const bool vx0 = (x0 >= 0) & (x0 < WW);
        const bool vx1 = (x0 + 1 >= 0) & (x0 + 1 < WW);
        w00 = (vy0 & vx0) ? w00 : 0.f;
        w01 = (vy0 & vx1) ? w01 : 0.f;
        w10 = (vy1 & vx0) ? w10 : 0.f;
        w11 = (vy1 & vx1) ? w11 : 0.f;
        const int cy0 = min(max(y0, 0), HH - 1);
        const int cy1 = min(max(y0 + 1, 0), HH - 1);
        const int cx0 = min(max(x0, 0), WW - 1);
        const int cx1 = min(max(x0 + 1, 0), WW - 1);
        const short8 q00 = *(const short8*)(xb + (size_t)(cy0 * WW + cx0) * 64 + cofs);
        const short8 q01 = *(const short8*)(xb + (size_t)(cy0 * WW + cx1) * 64 + cofs);
        const short8 q10 = *(const short8*)(xb + (size_t)(cy1 * WW + cx0) * 64 + cofs);
        const short8 q11 = *(const short8*)(xb + (size_t)(cy1 * WW + cx1) * 64 + cofs);
        unsigned short sv[8];
        #pragma unroll
        for (int j = 0; j < 8; ++j) {
          const float sval = w00 * bf2f((unsigned short)q00[j]) + w01 * bf2f((unsigned short)q01[j])
                           + w10 * bf2f((unsigned short)q10[j]) + w11 * bf2f((unsigned short)q11[j]);
          sv[j] = f2bf(sval);
        }
        pf = *(const short8*)sv;
      }
      #pragma unroll
      for (int mf = 0; mf < 4; ++mf) {
        const short8 wf = *(const short8*)(wdf + ((size_t)((g * 5 + s) * 4 + mf)) * 512 + l * 8);
        acc[mf] = __builtin_amdgcn_mfma_f32_16x16x32_bf16(wf, pf, acc[mf], 0, 0, 0);
      }
    }
  }

  // D: col = px (l15), row = o -> coalesced px stores
  float* ob = out + (size_t)b * 64 * HW_;
  #pragma unroll
  for (int mf = 0; mf < 4; ++mf) {
    #pragma unroll
    for (int r = 0; r < 4; ++r) {
      const int o = mf * 16 + lg * 4 + r;
      ob[(size_t)o * HW_ + p_img] = lrelu_f(acc[mf][r] + bias[o]);
    }
  }
}

extern "C" void kernel_launch(void* const* d_in, const int* in_sizes, int n_in,
                              void* d_out, int out_size, void* d_ws, size_t ws_size,
                              hipStream_t stream) {
  const float* nbr   = (const float*)d_in[0];
  const float* ref   = (const float*)d_in[1];
  const float* w_co1 = (const float*)d_in[2];
  const float* b_co1 = (const float*)d_in[3];
  const float* w_m1  = (const float*)d_in[4];
  const float* b_m1  = (const float*)d_in[5];
  const float* w_m2  = (const float*)d_in[6];
  const float* b_m2  = (const float*)d_in[7];
  const float* w_m3  = (const float*)d_in[8];
  const float* b_m3  = (const float*)d_in[9];
  const float* w_dcn = (const float*)d_in[10];
  const float* b_dcn = (const float*)d_in[11];
  float* out = (float*)d_out;

  char* ws = (char*)d_ws;
  // Lifetime-packed plan (~61.0 MB):
  //  [0, 14.68M)        xnb  [B][HW][64]   (persistent -> dcn)
  //  [14.68M, 44.04M)   x1t  [B][HW][128]  (dead after conv1)
  //     m1t aliases [14.68M, 29.36M), m2t aliases [29.36M, 44.04M)
  //  [44.04M, 58.72M)   featt (dead after m1); offt aliases [44.04M, 60.56M)
  //  [60.56M, +487424)  weights
  unsigned short* xnb   = (unsigned short*)(ws);
  unsigned short* x1t   = (unsigned short*)(ws + 14680064);
  unsigned short* m1t   = (unsigned short*)(ws + 14680064);   // alias (after conv1)
  unsigned short* m2t   = (unsigned short*)(ws + 29360128);   // alias
  unsigned short* featt = (unsigned short*)(ws + 44040192);
  unsigned short* offt  = (unsigned short*)(ws + 44040192);   // alias (after m1)
  char* wbase = ws + 60555264;
  unsigned short* wf1  = (unsigned short*)(wbase);            // 9*4*4*512*2  = 147456
  unsigned short* wfm1 = (unsigned short*)(wbase + 147456);   // 9*2*4*512*2  = 73728
  unsigned short* wfm2 = (unsigned short*)(wbase + 221184);   // 73728
  unsigned short* wfm3 = (unsigned short*)(wbase + 294912);   // 9*2*6*512*2  = 110592
  unsigned short* wdf  = (unsigned short*)(wbase + 405504);   // 40960*2      = 81920

  dim3 blk(256);
  prep_wfrag<<<dim3(288), blk, 0, stream>>>(w_co1, wf1, 64, 128, 4);
  prep_wfrag<<<dim3(144), blk, 0, stream>>>(w_m1, wfm1, 64, 64, 4);
  prep_wfrag<<<dim3(144), blk, 0, stream>>>(w_m2, wfm2, 64, 64, 4);
  prep_wfrag<<<dim3(216), blk, 0, stream>>>(w_m3, wfm3, 72, 64, 6);
  prep_wdcnf<<<dim3(160), blk, 0, stream>>>(w_dcn, wdf);
  prep_xt<<<dim3(448, 4), blk, 0, stream>>>(nbr, ref, x1t, xnb);

  conv_mfma<128, 4, 64, true><<<dim3(112, 4), blk, 0, stream>>>(x1t, wf1, b_co1, featt, 64);
  conv_lds<2, 4, 64, true ><<<dim3(112, 4, 2), blk, 0, stream>>>(featt, wfm1, b_m1, m1t, 64);
  conv_lds<2, 4, 64, true ><<<dim3(112, 4, 2), blk, 0, stream>>>(m1t,   wfm2, b_m2, m2t, 64);
  conv_lds<3, 6, 72, false><<<dim3(112, 4, 2), blk, 0, stream>>>(m2t,   wfm3, b_m3, offt, 72);
  dcn_v4<<<dim3(448, 4), blk, 0, stream>>>(xnb, offt, wdf, b_dcn, out);
}

// Round 9
// 250.248 us; speedup vs baseline: 1.6870x; 1.0333x over previous
//
#include <hip/hip_runtime.h>

#define HH 128
#define WW 224
#define HW_ (HH * WW)   // 28672

typedef short short8 __attribute__((ext_vector_type(8)));
typedef float f32x4 __attribute__((ext_vector_type(4)));

__device__ __forceinline__ float lrelu_f(float v) { return v >= 0.f ? v : 0.1f * v; }

__device__ __forceinline__ unsigned short f2bf(float f) {
  union { float f; unsigned u; } x; x.f = f;
  unsigned r = x.u + 0x7fff + ((x.u >> 16) & 1);   // RNE
  return (unsigned short)(r >> 16);
}
__device__ __forceinline__ float bf2f(unsigned short u) {
  union { unsigned u; float f; } x; x.u = ((unsigned)u) << 16; return x.f;
}

// ---- prep: concat(nbr,ref) -> x1t[b][p][128] bf16; also xnb[b][p][64] (nbr only) ----
__global__ __launch_bounds__(256)
void prep_xt(const float* __restrict__ nbr, const float* __restrict__ ref,
             unsigned short* __restrict__ xt, unsigned short* __restrict__ xnb) {
  const int lane = threadIdx.x & 63;
  const int q = threadIdx.x >> 6;          // channel quarter (32 ch)
  const int p = blockIdx.x * 64 + lane;
  const int b = blockIdx.y;
  const int c0 = q * 32;
  const float* src = (c0 < 64) ? (nbr + ((size_t)b * 64 + c0) * HW_)
                               : (ref + ((size_t)b * 64 + (c0 - 64)) * HW_);
  unsigned short tmp[32];
  #pragma unroll
  for (int i = 0; i < 32; ++i) tmp[i] = f2bf(src[(size_t)i * HW_ + p]);
  unsigned short* dst = xt + ((size_t)b * HW_ + p) * 128 + c0;
  #pragma unroll
  for (int i = 0; i < 4; ++i)
    *(short8*)(dst + i * 8) = *(const short8*)(tmp + i * 8);
  if (c0 < 64) {
    unsigned short* dst2 = xnb + ((size_t)b * HW_ + p) * 64 + c0;
    #pragma unroll
    for (int i = 0; i < 4; ++i)
      *(short8*)(dst2 + i * 8) = *(const short8*)(tmp + i * 8);
  }
}

// ---- prep: conv weight [O][C][9] fp32 -> fragment-ordered bf16
//      wt[((k*CB + cb)*NFT + nfg)*512 + lane*8 + j], o = nfg*16+(lane&15),
//      c = cb*32+(lane>>4)*8+j ----
__global__ void prep_wfrag(const float* __restrict__ w, unsigned short* __restrict__ wt,
                           int O, int C, int NFT) {
  const int i = blockIdx.x * 256 + threadIdx.x;
  const int CB = C / 32;
  const int total = 9 * CB * NFT * 512;
  if (i >= total) return;
  const int j = i & 7;
  const int lane = (i >> 3) & 63;
  const int fid = i >> 9;
  const int nfg = fid % NFT;
  const int kcb = fid / NFT;
  const int cb = kcb % CB;
  const int k = kcb / CB;
  const int o = nfg * 16 + (lane & 15);
  const int c = cb * 32 + (lane >> 4) * 8 + j;
  float v = (o < O) ? w[((size_t)o * C + c) * 9 + k] : 0.f;
  wt[i] = f2bf(v);
}

// ---- prep: dcn weight [O=64][C=64][9] -> fragment-ordered, K padded to 160/group
//      wt[((g*5+s)*4+mf)*512 + lane*8 + j]: o=mf*16+l15, t=2s+(lg>>1), c=g*16+(lg&1)*8+j ----
__global__ void prep_wdcnf(const float* __restrict__ w, unsigned short* __restrict__ wt) {
  const int i = blockIdx.x * 256 + threadIdx.x;   // 40960
  if (i >= 40960) return;
  const int j = i & 7;
  const int lane = (i >> 3) & 63;
  const int fid = i >> 9;
  const int mf = fid & 3;
  const int s = (fid >> 2) % 5;
  const int g = fid / 20;
  const int l15 = lane & 15, lg = lane >> 4;
  const int o = mf * 16 + l15;
  const int t = 2 * s + (lg >> 1);
  const int c = g * 16 + (lg & 1) * 8 + j;
  float v = (t < 9) ? w[((size_t)o * 64 + c) * 9 + t] : 0.f;
  wt[i] = f2bf(v);
}

// ---- conv via LDS-staged 8x32 tile + 1px halo (10x34 rows, XOR-swizzled). ----
// Block: 256 thr = 4 waves; wave = rows {2w,2w+1} x 32 cols = 64 px x NFT*16 outputs.
// CINB = input 64-ch blocks (1 or 2); staged/computed sequentially in same LDS.
template<int CINB, int NFT, int CROW, bool LRELU>
__global__ __launch_bounds__(256, 3)
void conv_lds(const unsigned short* __restrict__ xt, const unsigned short* __restrict__ wfrag,
              const float* __restrict__ bias, unsigned short* __restrict__ out, int coutReal) {
  __shared__ __align__(16) char xs[10 * 34 * 128];   // 43520 B
  const int tid = threadIdx.x;
  const int lane = tid & 63, wv = tid >> 6;
  const int l15 = lane & 15, lg = lane >> 4;
  const int b = blockIdx.y;
  const int ty = (blockIdx.x / 7) * 8, tx = (blockIdx.x % 7) * 32;
  const int CIN = CINB * 64;
  const unsigned short* xb = xt + (size_t)b * HW_ * CIN;

  f32x4 acc[4][NFT];
  #pragma unroll
  for (int mf = 0; mf < 4; ++mf)
    #pragma unroll
    for (int nf = 0; nf < NFT; ++nf) acc[mf][nf] = (f32x4){0.f, 0.f, 0.f, 0.f};

  #pragma unroll 1
  for (int cb2 = 0; cb2 < CINB; ++cb2) {
    if (cb2 > 0) __syncthreads();   // WAR: previous compute must finish before restage
    // stage halo tile: 340 px rows x 128 B (64 ch slice), coalesced, zero-fill OOB
    for (int ci = tid; ci < 2720; ci += 256) {
      const int ch = ci & 7;
      const int hp = ci >> 3;
      const int hr = hp / 34, hc = hp % 34;
      const int gy = ty + hr - 1, gx = tx + hc - 1;
      short8 v = (short8)0;
      if (((unsigned)gy < HH) & ((unsigned)gx < WW))
        v = *(const short8*)(xb + (size_t)(gy * WW + gx) * CIN + cb2 * 64 + ch * 8);
      *(short8*)(xs + hp * 128 + ((ch * 16) ^ ((hc & 7) << 4))) = v;
    }
    __syncthreads();

    #pragma unroll 2
    for (int k = 0; k < 9; ++k) {
      const int ky = k / 3, kx = k % 3;   // halo offset +1 folded in
      #pragma unroll
      for (int cb = 0; cb < 2; ++cb) {
        short8 av[4];
        #pragma unroll
        for (int mf = 0; mf < 4; ++mf) {
          const int hr = 2 * wv + (mf >> 1) + ky;
          const int hc = (mf & 1) * 16 + l15 + kx;
          av[mf] = *(const short8*)(xs + (hr * 34 + hc) * 128
                                    + ((cb * 64 + lg * 16) ^ ((hc & 7) << 4)));
        }
        #pragma unroll
        for (int nf = 0; nf < NFT; ++nf) {
          const short8 bv = *(const short8*)(wfrag
              + ((size_t)((k * (CINB * 2) + cb2 * 2 + cb) * NFT + nf)) * 512 + lane * 8);
          #pragma unroll
          for (int mf = 0; mf < 4; ++mf)
            acc[mf][nf] = __builtin_amdgcn_mfma_f32_16x16x32_bf16(av[mf], bv, acc[mf][nf], 0, 0, 0);
        }
      }
    }
  }

  unsigned short* ob = out + (size_t)b * HW_ * CROW;
  #pragma unroll
  for (int nf = 0; nf < NFT; ++nf) {
    const int o = nf * 16 + l15;
    const bool ov = (o < coutReal);
    const float bz = ov ? bias[o] : 0.f;
    #pragma unroll
    for (int mf = 0; mf < 4; ++mf) {
      const int rr = ty + 2 * wv + (mf >> 1);
      #pragma unroll
      for (int r = 0; r < 4; ++r) {
        const int cc = tx + (mf & 1) * 16 + lg * 4 + r;
        float vv = acc[mf][nf][r] + bz;
        if (LRELU) vv = lrelu_f(vv);
        if (ov) ob[(size_t)(rr * WW + cc) * CROW + o] = f2bf(vv);
      }
    }
  }
}

// ---- DCN v4b: register-direct MFMA, 2-D tiled (16x4 px/block) + XCD-banded swizzle ----
__global__ __launch_bounds__(256, 3)
void dcn_v4(const unsigned short* __restrict__ xnb,  // [B][HW][64] bf16
            const unsigned short* __restrict__ offt, // [B][HW][72] bf16
            const unsigned short* __restrict__ wdf,  // fragment-ordered [80 fids][512]
            const float* __restrict__ bias, float* __restrict__ out) {
  const int tid = threadIdx.x;
  const int w = tid >> 6, l = tid & 63;
  const int l15 = l & 15, lg = l >> 4;
  const int b = blockIdx.y;
  // 448 tiles of 16x4: swizzle so each XCD owns a contiguous 16-row band
  const int bx = blockIdx.x;
  const int swz = (bx & 7) * 56 + (bx >> 3);       // bijective: 448 = 8*56
  const int tx = (swz % 14) * 16;
  const int ty = (swz / 14) * 4;
  const int y = ty + w;
  const int x = tx + l15;
  const int p_img = y * WW + x;
  const unsigned short* xb = xnb + (size_t)b * HW_ * 64;
  const unsigned* od = (const unsigned*)(offt + ((size_t)b * HW_ + p_img) * 72);
  const int thalf = lg >> 1;
  const int cofs0 = (lg & 1) * 8;

  f32x4 acc[4];
  #pragma unroll
  for (int mf = 0; mf < 4; ++mf) acc[mf] = (f32x4){0.f, 0.f, 0.f, 0.f};

  #pragma unroll 1
  for (int g = 0; g < 4; ++g) {
    const int cofs = g * 16 + cofs0;
    #pragma unroll 2
    for (int s = 0; s < 5; ++s) {
      const int t = 2 * s + thalf;
      short8 pf = (short8)0;
      if (t < 9) {
        const unsigned dpair = od[g * 9 + t];
        const float dy = bf2f((unsigned short)(dpair & 0xffff));
        const float dx = bf2f((unsigned short)(dpair >> 16));
        const float sy = dy + (float)(y - 1 + t / 3);
        const float sx = dx + (float)(x - 1 + t % 3);
        const float fy = floorf(sy);
        const float fx = floorf(sx);
        const int y0 = (int)fy;
        const int x0 = (int)fx;
        const float ay = sy - fy;
        const float ax = sx - fx;
        float w00 = (1.f - ay) * (1.f - ax);
        float w01 = (1.f - ay) * ax;
        float w10 = ay * (1.f - ax);
        float w11 = ay * ax;
        const bool vy0 = (y0 >= 0) & (y0 < HH);
        const bool vy1 = (y0 + 1 >= 0) & (y0 + 1 < HH);
        const bool vx0 = (x0 >= 0) & (x0 < WW);
        const bool vx1 = (x0 + 1 >= 0) & (x0 + 1 < WW);
        w00 = (vy0 & vx0) ? w00 : 0.f;
        w01 = (vy0 & vx1) ? w01 : 0.f;
        w10 = (vy1 & vx0) ? w10 : 0.f;
        w11 = (vy1 & vx1) ? w11 : 0.f;
        const int cy0 = min(max(y0, 0), HH - 1);
        const int cy1 = min(max(y0 + 1, 0), HH - 1);
        const int cx0 = min(max(x0, 0), WW - 1);
        const int cx1 = min(max(x0 + 1, 0), WW - 1);
        const short8 q00 = *(const short8*)(xb + (size_t)(cy0 * WW + cx0) * 64 + cofs);
        const short8 q01 = *(const short8*)(xb + (size_t)(cy0 * WW + cx1) * 64 + cofs);
        const short8 q10 = *(const short8*)(xb + (size_t)(cy1 * WW + cx0) * 64 + cofs);
        const short8 q11 = *(const short8*)(xb + (size_t)(cy1 * WW + cx1) * 64 + cofs);
        unsigned short sv[8];
        #pragma unroll
        for (int j = 0; j < 8; ++j) {
          const float sval = w00 * bf2f((unsigned short)q00[j]) + w01 * bf2f((unsigned short)q01[j])
                           + w10 * bf2f((unsigned short)q10[j]) + w11 * bf2f((unsigned short)q11[j]);
          sv[j] = f2bf(sval);
        }
        pf = *(const short8*)sv;
      }
      #pragma unroll
      for (int mf = 0; mf < 4; ++mf) {
        const short8 wf = *(const short8*)(wdf + ((size_t)((g * 5 + s) * 4 + mf)) * 512 + l * 8);
        acc[mf] = __builtin_amdgcn_mfma_f32_16x16x32_bf16(wf, pf, acc[mf], 0, 0, 0);
      }
    }
  }

  // D: col = px (l15), row = o -> coalesced 64B px stores
  float* ob = out + (size_t)b * 64 * HW_;
  #pragma unroll
  for (int mf = 0; mf < 4; ++mf) {
    #pragma unroll
    for (int r = 0; r < 4; ++r) {
      const int o = mf * 16 + lg * 4 + r;
      ob[(size_t)o * HW_ + p_img] = lrelu_f(acc[mf][r] + bias[o]);
    }
  }
}

extern "C" void kernel_launch(void* const* d_in, const int* in_sizes, int n_in,
                              void* d_out, int out_size, void* d_ws, size_t ws_size,
                              hipStream_t stream) {
  const float* nbr   = (const float*)d_in[0];
  const float* ref   = (const float*)d_in[1];
  const float* w_co1 = (const float*)d_in[2];
  const float* b_co1 = (const float*)d_in[3];
  const float* w_m1  = (const float*)d_in[4];
  const float* b_m1  = (const float*)d_in[5];
  const float* w_m2  = (const float*)d_in[6];
  const float* b_m2  = (const float*)d_in[7];
  const float* w_m3  = (const float*)d_in[8];
  const float* b_m3  = (const float*)d_in[9];
  const float* w_dcn = (const float*)d_in[10];
  const float* b_dcn = (const float*)d_in[11];
  float* out = (float*)d_out;

  char* ws = (char*)d_ws;
  // Lifetime-packed plan (~61.0 MB):
  //  [0, 14.68M)        xnb  [B][HW][64]   (persistent -> dcn)
  //  [14.68M, 44.04M)   x1t  [B][HW][128]  (dead after conv1)
  //     m1t aliases [14.68M, 29.36M), m2t aliases [29.36M, 44.04M)
  //  [44.04M, 58.72M)   featt (dead after m1); offt aliases [44.04M, 60.56M)
  //  [60.56M, +468992)  weights
  unsigned short* xnb   = (unsigned short*)(ws);
  unsigned short* x1t   = (unsigned short*)(ws + 14680064);
  unsigned short* m1t   = (unsigned short*)(ws + 14680064);   // alias (after conv1)
  unsigned short* m2t   = (unsigned short*)(ws + 29360128);   // alias
  unsigned short* featt = (unsigned short*)(ws + 44040192);
  unsigned short* offt  = (unsigned short*)(ws + 44040192);   // alias (after m1)
  char* wbase = ws + 60555264;
  unsigned short* wf1  = (unsigned short*)(wbase);            // 9*4*4*512*2  = 147456
  unsigned short* wfm1 = (unsigned short*)(wbase + 147456);   // 9*2*4*512*2  = 73728
  unsigned short* wfm2 = (unsigned short*)(wbase + 221184);   // 73728
  unsigned short* wfm3 = (unsigned short*)(wbase + 294912);   // 9*2*5*512*2  = 92160
  unsigned short* wdf  = (unsigned short*)(wbase + 387072);   // 40960*2      = 81920

  dim3 blk(256);
  prep_wfrag<<<dim3(288), blk, 0, stream>>>(w_co1, wf1, 64, 128, 4);
  prep_wfrag<<<dim3(144), blk, 0, stream>>>(w_m1, wfm1, 64, 64, 4);
  prep_wfrag<<<dim3(144), blk, 0, stream>>>(w_m2, wfm2, 64, 64, 4);
  prep_wfrag<<<dim3(180), blk, 0, stream>>>(w_m3, wfm3, 72, 64, 5);
  prep_wdcnf<<<dim3(160), blk, 0, stream>>>(w_dcn, wdf);
  prep_xt<<<dim3(448, 4), blk, 0, stream>>>(nbr, ref, x1t, xnb);

  conv_lds<2, 4, 64, true ><<<dim3(112, 4), blk, 0, stream>>>(x1t,   wf1,  b_co1, featt, 64);
  conv_lds<1, 4, 64, true ><<<dim3(112, 4), blk, 0, stream>>>(featt, wfm1, b_m1,  m1t,   64);
  conv_lds<1, 4, 64, true ><<<dim3(112, 4), blk, 0, stream>>>(m1t,   wfm2, b_m2,  m2t,   64);
  conv_lds<1, 5, 72, false><<<dim3(112, 4), blk, 0, stream>>>(m2t,   wfm3, b_m3,  offt,  72);
  dcn_v4<<<dim3(448, 4), blk, 0, stream>>>(xnb, offt, wdf, b_dcn, out);
}

// Round 10
// 229.575 us; speedup vs baseline: 1.8389x; 1.0900x over previous
//
#include <hip/hip_runtime.h>

#define HH 128
#define WW 224
#define HW_ (HH * WW)   // 28672

typedef short short8 __attribute__((ext_vector_type(8)));
typedef float f32x4 __attribute__((ext_vector_type(4)));

__device__ __forceinline__ float lrelu_f(float v) { return v >= 0.f ? v : 0.1f * v; }

__device__ __forceinline__ unsigned short f2bf(float f) {
  union { float f; unsigned u; } x; x.f = f;
  unsigned r = x.u + 0x7fff + ((x.u >> 16) & 1);   // RNE
  return (unsigned short)(r >> 16);
}
__device__ __forceinline__ float bf2f(unsigned short u) {
  union { unsigned u; float f; } x; x.u = ((unsigned)u) << 16; return x.f;
}

// ---- prep: concat(nbr,ref) -> x1t[b][p][128] bf16; also xnb[b][p][64] (nbr only) ----
__global__ __launch_bounds__(256)
void prep_xt(const float* __restrict__ nbr, const float* __restrict__ ref,
             unsigned short* __restrict__ xt, unsigned short* __restrict__ xnb) {
  const int lane = threadIdx.x & 63;
  const int q = threadIdx.x >> 6;          // channel quarter (32 ch)
  const int p = blockIdx.x * 64 + lane;
  const int b = blockIdx.y;
  const int c0 = q * 32;
  const float* src = (c0 < 64) ? (nbr + ((size_t)b * 64 + c0) * HW_)
                               : (ref + ((size_t)b * 64 + (c0 - 64)) * HW_);
  unsigned short tmp[32];
  #pragma unroll
  for (int i = 0; i < 32; ++i) tmp[i] = f2bf(src[(size_t)i * HW_ + p]);
  unsigned short* dst = xt + ((size_t)b * HW_ + p) * 128 + c0;
  #pragma unroll
  for (int i = 0; i < 4; ++i)
    *(short8*)(dst + i * 8) = *(const short8*)(tmp + i * 8);
  if (c0 < 64) {
    unsigned short* dst2 = xnb + ((size_t)b * HW_ + p) * 64 + c0;
    #pragma unroll
    for (int i = 0; i < 4; ++i)
      *(short8*)(dst2 + i * 8) = *(const short8*)(tmp + i * 8);
  }
}

// ---- prep: conv weight [O][C][9] fp32 -> fragment-ordered bf16 ----
__global__ void prep_wfrag(const float* __restrict__ w, unsigned short* __restrict__ wt,
                           int O, int C, int NFT) {
  const int i = blockIdx.x * 256 + threadIdx.x;
  const int CB = C / 32;
  const int total = 9 * CB * NFT * 512;
  if (i >= total) return;
  const int j = i & 7;
  const int lane = (i >> 3) & 63;
  const int fid = i >> 9;
  const int nfg = fid % NFT;
  const int kcb = fid / NFT;
  const int cb = kcb % CB;
  const int k = kcb / CB;
  const int o = nfg * 16 + (lane & 15);
  const int c = cb * 32 + (lane >> 4) * 8 + j;
  float v = (o < O) ? w[((size_t)o * C + c) * 9 + k] : 0.f;
  wt[i] = f2bf(v);
}

// ---- prep: dcn weight -> fragment-ordered, K padded to 160/group ----
__global__ void prep_wdcnf(const float* __restrict__ w, unsigned short* __restrict__ wt) {
  const int i = blockIdx.x * 256 + threadIdx.x;   // 40960
  if (i >= 40960) return;
  const int j = i & 7;
  const int lane = (i >> 3) & 63;
  const int fid = i >> 9;
  const int mf = fid & 3;
  const int s = (fid >> 2) % 5;
  const int g = fid / 20;
  const int l15 = lane & 15, lg = lane >> 4;
  const int o = mf * 16 + l15;
  const int t = 2 * s + (lg >> 1);
  const int c = g * 16 + (lg & 1) * 8 + j;
  float v = (t < 9) ? w[((size_t)o * 64 + c) * 9 + t] : 0.f;
  wt[i] = f2bf(v);
}

// ---- conv via LDS-staged 8x32 tile + 1px halo (10x34 rows, XOR-swizzled). ----
template<int CINB, int NFT, int CROW, bool LRELU>
__global__ __launch_bounds__(256, 3)
void conv_lds(const unsigned short* __restrict__ xt, const unsigned short* __restrict__ wfrag,
              const float* __restrict__ bias, unsigned short* __restrict__ out, int coutReal) {
  __shared__ __align__(16) char xs[10 * 34 * 128];   // 43520 B
  const int tid = threadIdx.x;
  const int lane = tid & 63, wv = tid >> 6;
  const int l15 = lane & 15, lg = lane >> 4;
  const int b = blockIdx.y;
  const int ty = (blockIdx.x / 7) * 8, tx = (blockIdx.x % 7) * 32;
  const int CIN = CINB * 64;
  const unsigned short* xb = xt + (size_t)b * HW_ * CIN;

  f32x4 acc[4][NFT];
  #pragma unroll
  for (int mf = 0; mf < 4; ++mf)
    #pragma unroll
    for (int nf = 0; nf < NFT; ++nf) acc[mf][nf] = (f32x4){0.f, 0.f, 0.f, 0.f};

  #pragma unroll 1
  for (int cb2 = 0; cb2 < CINB; ++cb2) {
    if (cb2 > 0) __syncthreads();
    for (int ci = tid; ci < 2720; ci += 256) {
      const int ch = ci & 7;
      const int hp = ci >> 3;
      const int hr = hp / 34, hc = hp % 34;
      const int gy = ty + hr - 1, gx = tx + hc - 1;
      short8 v = (short8)0;
      if (((unsigned)gy < HH) & ((unsigned)gx < WW))
        v = *(const short8*)(xb + (size_t)(gy * WW + gx) * CIN + cb2 * 64 + ch * 8);
      *(short8*)(xs + hp * 128 + ((ch * 16) ^ ((hc & 7) << 4))) = v;
    }
    __syncthreads();

    #pragma unroll 2
    for (int k = 0; k < 9; ++k) {
      const int ky = k / 3, kx = k % 3;
      #pragma unroll
      for (int cb = 0; cb < 2; ++cb) {
        short8 av[4];
        #pragma unroll
        for (int mf = 0; mf < 4; ++mf) {
          const int hr = 2 * wv + (mf >> 1) + ky;
          const int hc = (mf & 1) * 16 + l15 + kx;
          av[mf] = *(const short8*)(xs + (hr * 34 + hc) * 128
                                    + ((cb * 64 + lg * 16) ^ ((hc & 7) << 4)));
        }
        #pragma unroll
        for (int nf = 0; nf < NFT; ++nf) {
          const short8 bv = *(const short8*)(wfrag
              + ((size_t)((k * (CINB * 2) + cb2 * 2 + cb) * NFT + nf)) * 512 + lane * 8);
          #pragma unroll
          for (int mf = 0; mf < 4; ++mf)
            acc[mf][nf] = __builtin_amdgcn_mfma_f32_16x16x32_bf16(av[mf], bv, acc[mf][nf], 0, 0, 0);
        }
      }
    }
  }

  unsigned short* ob = out + (size_t)b * HW_ * CROW;
  #pragma unroll
  for (int nf = 0; nf < NFT; ++nf) {
    const int o = nf * 16 + l15;
    const bool ov = (o < coutReal);
    const float bz = ov ? bias[o] : 0.f;
    #pragma unroll
    for (int mf = 0; mf < 4; ++mf) {
      const int rr = ty + 2 * wv + (mf >> 1);
      #pragma unroll
      for (int r = 0; r < 4; ++r) {
        const int cc = tx + (mf & 1) * 16 + lg * 4 + r;
        float vv = acc[mf][nf][r] + bz;
        if (LRELU) vv = lrelu_f(vv);
        if (ov) ob[(size_t)(rr * WW + cc) * CROW + o] = f2bf(vv);
      }
    }
  }
}

// ---- DCN v5: LDS-staged halo sampling (12x24 px, 64ch), register-direct MFMA. ----
// Tile 16x4 px/block, XCD-banded swizzle. Corners with |off|<=2.5 hit LDS (fast);
// wave-uniform fallback to global gathers keeps arbitrary offsets correct.
__global__ __launch_bounds__(256, 3)
void dcn_v5(const unsigned short* __restrict__ xnb,  // [B][HW][64] bf16
            const unsigned short* __restrict__ offt, // [B][HW][72] bf16
            const unsigned short* __restrict__ wdf,  // fragment-ordered [80 fids][512]
            const float* __restrict__ bias, float* __restrict__ out) {
  __shared__ __align__(16) char xs[12 * 24 * 128];   // 36864 B
  const int tid = threadIdx.x;
  const int w = tid >> 6, l = tid & 63;
  const int l15 = l & 15, lg = l >> 4;
  const int b = blockIdx.y;
  const int bx = blockIdx.x;
  const int swz = (bx & 7) * 56 + (bx >> 3);       // bijective: 448 = 8*56
  const int tx = (swz % 14) * 16;
  const int ty = (swz / 14) * 4;
  const int y = ty + w;
  const int x = tx + l15;
  const int p_img = y * WW + x;
  const unsigned short* xb = xnb + (size_t)b * HW_ * 64;

  // stage halo: rows [ty-4, ty+8), cols [tx-4, tx+20), zero-fill out-of-image
  for (int ci = tid; ci < 2304; ci += 256) {     // 12*24*8, exactly 9 iters
    const int ch = ci & 7;
    const int pos = ci >> 3;
    const int r = pos / 24, c = pos % 24;
    const int gy = ty - 4 + r, gx = tx - 4 + c;
    short8 v = (short8)0;
    if (((unsigned)gy < HH) & ((unsigned)gx < WW))
      v = *(const short8*)(xb + (size_t)(gy * WW + gx) * 64 + ch * 8);
    *(short8*)(xs + pos * 128 + ((ch * 16) ^ (((r + c) & 7) << 4))) = v;
  }
  __syncthreads();

  const unsigned* od = (const unsigned*)(offt + ((size_t)b * HW_ + p_img) * 72);
  const int thalf = lg >> 1;
  const int cofs0 = (lg & 1) * 8;

  f32x4 acc[4];
  #pragma unroll
  for (int mf = 0; mf < 4; ++mf) acc[mf] = (f32x4){0.f, 0.f, 0.f, 0.f};

  #pragma unroll 1
  for (int g = 0; g < 4; ++g) {
    const int cofs = g * 16 + cofs0;
    const int chunkB = cofs * 2;                   // byte offset within 128B row
    #pragma unroll 1
    for (int s = 0; s < 5; ++s) {
      const int t = 2 * s + thalf;
      const bool live = (t < 9);
      // coordinate + weight math (garbage for dead lanes, unused)
      const unsigned dpair = od[g * 9 + (live ? t : 0)];
      const float dy = bf2f((unsigned short)(dpair & 0xffff));
      const float dx = bf2f((unsigned short)(dpair >> 16));
      const float sy = dy + (float)(y - 1 + t / 3);
      const float sx = dx + (float)(x - 1 + t % 3);
      const float fy = floorf(sy);
      const float fx = floorf(sx);
      const int y0 = (int)fy;
      const int x0 = (int)fx;
      const float ay = sy - fy;
      const float ax = sx - fx;
      float w00 = (1.f - ay) * (1.f - ax);
      float w01 = (1.f - ay) * ax;
      float w10 = ay * (1.f - ax);
      float w11 = ay * ax;
      const bool vy0 = (y0 >= 0) & (y0 < HH);
      const bool vy1 = (y0 + 1 >= 0) & (y0 + 1 < HH);
      const bool vx0 = (x0 >= 0) & (x0 < WW);
      const bool vx1 = (x0 + 1 >= 0) & (x0 + 1 < WW);
      w00 = (vy0 & vx0) ? w00 : 0.f;
      w01 = (vy0 & vx1) ? w01 : 0.f;
      w10 = (vy1 & vx0) ? w10 : 0.f;
      w11 = (vy1 & vx1) ? w11 : 0.f;
      const int cy0 = min(max(y0, 0), HH - 1);
      const int cy1 = min(max(y0 + 1, 0), HH - 1);
      const int cx0 = min(max(x0, 0), WW - 1);
      const int cx1 = min(max(x0 + 1, 0), WW - 1);
      // tile-relative coords
      const int ry0 = cy0 - ty + 4, ry1 = cy1 - ty + 4;
      const int rx0 = cx0 - tx + 4, rx1 = cx1 - tx + 4;
      const bool inT = !live | (((unsigned)ry0 < 12u) & ((unsigned)ry1 < 12u)
                              & ((unsigned)rx0 < 24u) & ((unsigned)rx1 < 24u));
      short8 q00, q01, q10, q11;
      if (__all((int)inT)) {
        const int a00 = (ry0 * 24 + rx0) * 128 + (chunkB ^ (((ry0 + rx0) & 7) << 4));
        const int a01 = (ry0 * 24 + rx1) * 128 + (chunkB ^ (((ry0 + rx1) & 7) << 4));
        const int a10 = (ry1 * 24 + rx0) * 128 + (chunkB ^ (((ry1 + rx0) & 7) << 4));
        const int a11 = (ry1 * 24 + rx1) * 128 + (chunkB ^ (((ry1 + rx1) & 7) << 4));
        q00 = *(const short8*)(xs + a00);
        q01 = *(const short8*)(xs + a01);
        q10 = *(const short8*)(xs + a10);
        q11 = *(const short8*)(xs + a11);
      } else {
        q00 = *(const short8*)(xb + (size_t)(cy0 * WW + cx0) * 64 + cofs);
        q01 = *(const short8*)(xb + (size_t)(cy0 * WW + cx1) * 64 + cofs);
        q10 = *(const short8*)(xb + (size_t)(cy1 * WW + cx0) * 64 + cofs);
        q11 = *(const short8*)(xb + (size_t)(cy1 * WW + cx1) * 64 + cofs);
      }
      short8 pf = (short8)0;
      if (live) {
        unsigned short sv[8];
        #pragma unroll
        for (int j = 0; j < 8; ++j) {
          const float sval = w00 * bf2f((unsigned short)q00[j]) + w01 * bf2f((unsigned short)q01[j])
                           + w10 * bf2f((unsigned short)q10[j]) + w11 * bf2f((unsigned short)q11[j]);
          sv[j] = f2bf(sval);
        }
        pf = *(const short8*)sv;
      }
      #pragma unroll
      for (int mf = 0; mf < 4; ++mf) {
        const short8 wf = *(const short8*)(wdf + ((size_t)((g * 5 + s) * 4 + mf)) * 512 + l * 8);
        acc[mf] = __builtin_amdgcn_mfma_f32_16x16x32_bf16(wf, pf, acc[mf], 0, 0, 0);
      }
    }
  }

  float* ob = out + (size_t)b * 64 * HW_;
  #pragma unroll
  for (int mf = 0; mf < 4; ++mf) {
    #pragma unroll
    for (int r = 0; r < 4; ++r) {
      const int o = mf * 16 + lg * 4 + r;
      ob[(size_t)o * HW_ + p_img] = lrelu_f(acc[mf][r] + bias[o]);
    }
  }
}

extern "C" void kernel_launch(void* const* d_in, const int* in_sizes, int n_in,
                              void* d_out, int out_size, void* d_ws, size_t ws_size,
                              hipStream_t stream) {
  const float* nbr   = (const float*)d_in[0];
  const float* ref   = (const float*)d_in[1];
  const float* w_co1 = (const float*)d_in[2];
  const float* b_co1 = (const float*)d_in[3];
  const float* w_m1  = (const float*)d_in[4];
  const float* b_m1  = (const float*)d_in[5];
  const float* w_m2  = (const float*)d_in[6];
  const float* b_m2  = (const float*)d_in[7];
  const float* w_m3  = (const float*)d_in[8];
  const float* b_m3  = (const float*)d_in[9];
  const float* w_dcn = (const float*)d_in[10];
  const float* b_dcn = (const float*)d_in[11];
  float* out = (float*)d_out;

  char* ws = (char*)d_ws;
  unsigned short* xnb   = (unsigned short*)(ws);
  unsigned short* x1t   = (unsigned short*)(ws + 14680064);
  unsigned short* m1t   = (unsigned short*)(ws + 14680064);   // alias (after conv1)
  unsigned short* m2t   = (unsigned short*)(ws + 29360128);   // alias
  unsigned short* featt = (unsigned short*)(ws + 44040192);
  unsigned short* offt  = (unsigned short*)(ws + 44040192);   // alias (after m1)
  char* wbase = ws + 60555264;
  unsigned short* wf1  = (unsigned short*)(wbase);            // 147456
  unsigned short* wfm1 = (unsigned short*)(wbase + 147456);   // 73728
  unsigned short* wfm2 = (unsigned short*)(wbase + 221184);   // 73728
  unsigned short* wfm3 = (unsigned short*)(wbase + 294912);   // 92160
  unsigned short* wdf  = (unsigned short*)(wbase + 387072);   // 81920

  dim3 blk(256);
  prep_wfrag<<<dim3(288), blk, 0, stream>>>(w_co1, wf1, 64, 128, 4);
  prep_wfrag<<<dim3(144), blk, 0, stream>>>(w_m1, wfm1, 64, 64, 4);
  prep_wfrag<<<dim3(144), blk, 0, stream>>>(w_m2, wfm2, 64, 64, 4);
  prep_wfrag<<<dim3(180), blk, 0, stream>>>(w_m3, wfm3, 72, 64, 5);
  prep_wdcnf<<<dim3(160), blk, 0, stream>>>(w_dcn, wdf);
  prep_xt<<<dim3(448, 4), blk, 0, stream>>>(nbr, ref, x1t, xnb);

  conv_lds<2, 4, 64, true ><<<dim3(112, 4), blk, 0, stream>>>(x1t,   wf1,  b_co1, featt, 64);
  conv_lds<1, 4, 64, true ><<<dim3(112, 4), blk, 0, stream>>>(featt, wfm1, b_m1,  m1t,   64);
  conv_lds<1, 4, 64, true ><<<dim3(112, 4), blk, 0, stream>>>(m1t,   wfm2, b_m2,  m2t,   64);
  conv_lds<1, 5, 72, false><<<dim3(112, 4), blk, 0, stream>>>(m2t,   wfm3, b_m3,  offt,  72);
  dcn_v5<<<dim3(448, 4), blk, 0, stream>>>(xnb, offt, wdf, b_dcn, out);
}

// Round 11
// 198.677 us; speedup vs baseline: 2.1249x; 1.1555x over previous
//
#include <hip/hip_runtime.h>

#define HH 128
#define WW 224
#define HW_ (HH * WW)   // 28672

typedef short short8 __attribute__((ext_vector_type(8)));
typedef float f32x4 __attribute__((ext_vector_type(4)));
typedef float float2v __attribute__((ext_vector_type(2)));

__device__ __forceinline__ float lrelu_f(float v) { return v >= 0.f ? v : 0.1f * v; }

__device__ __forceinline__ unsigned short f2bf(float f) {
  union { float f; unsigned u; } x; x.f = f;
  unsigned r = x.u + 0x7fff + ((x.u >> 16) & 1);   // RNE
  return (unsigned short)(r >> 16);
}
__device__ __forceinline__ float bf2f(unsigned short u) {
  union { unsigned u; float f; } x; x.u = ((unsigned)u) << 16; return x.f;
}
__device__ __forceinline__ float asf(unsigned u) {
  union { unsigned u; float f; } x; x.u = u; return x.f;
}

// ---- prep: concat(nbr,ref) -> x1t[b][p][128] bf16; also xnb[b][p][64] (nbr only) ----
__global__ __launch_bounds__(256)
void prep_xt(const float* __restrict__ nbr, const float* __restrict__ ref,
             unsigned short* __restrict__ xt, unsigned short* __restrict__ xnb) {
  const int lane = threadIdx.x & 63;
  const int q = threadIdx.x >> 6;
  const int p = blockIdx.x * 64 + lane;
  const int b = blockIdx.y;
  const int c0 = q * 32;
  const float* src = (c0 < 64) ? (nbr + ((size_t)b * 64 + c0) * HW_)
                               : (ref + ((size_t)b * 64 + (c0 - 64)) * HW_);
  unsigned short tmp[32];
  #pragma unroll
  for (int i = 0; i < 32; ++i) tmp[i] = f2bf(src[(size_t)i * HW_ + p]);
  unsigned short* dst = xt + ((size_t)b * HW_ + p) * 128 + c0;
  #pragma unroll
  for (int i = 0; i < 4; ++i)
    *(short8*)(dst + i * 8) = *(const short8*)(tmp + i * 8);
  if (c0 < 64) {
    unsigned short* dst2 = xnb + ((size_t)b * HW_ + p) * 64 + c0;
    #pragma unroll
    for (int i = 0; i < 4; ++i)
      *(short8*)(dst2 + i * 8) = *(const short8*)(tmp + i * 8);
  }
}

// ---- device helpers for weight conversion ----
__device__ __forceinline__ void wfrag_one(const float* __restrict__ w,
                                          unsigned short* __restrict__ wt,
                                          int i, int O, int C, int NFT) {
  const int CB = C / 32;
  const int j = i & 7;
  const int lane = (i >> 3) & 63;
  const int fid = i >> 9;
  const int nfg = fid % NFT;
  const int kcb = fid / NFT;
  const int cb = kcb % CB;
  const int k = kcb / CB;
  const int o = nfg * 16 + (lane & 15);
  const int c = cb * 32 + (lane >> 4) * 8 + j;
  float v = (o < O) ? w[((size_t)o * C + c) * 9 + k] : 0.f;
  wt[i] = f2bf(v);
}
__device__ __forceinline__ void wdcn_one(const float* __restrict__ w,
                                         unsigned short* __restrict__ wt, int i) {
  const int j = i & 7;
  const int lane = (i >> 3) & 63;
  const int fid = i >> 9;
  const int mf = fid & 3;
  const int s = (fid >> 2) % 5;
  const int g = fid / 20;
  const int l15 = lane & 15, lg = lane >> 4;
  const int o = mf * 16 + l15;
  const int t = 2 * s + (lg >> 1);
  const int c = g * 16 + (lg & 1) * 8 + j;
  float v = (t < 9) ? w[((size_t)o * 64 + c) * 9 + t] : 0.f;
  wt[i] = f2bf(v);
}

// ---- all weight preps merged into one kernel ----
__global__ void prep_weights(const float* __restrict__ w1, const float* __restrict__ wm1,
                             const float* __restrict__ wm2, const float* __restrict__ wm3,
                             const float* __restrict__ wdcn,
                             unsigned short* __restrict__ wf1, unsigned short* __restrict__ wfm1,
                             unsigned short* __restrict__ wfm2, unsigned short* __restrict__ wfm3,
                             unsigned short* __restrict__ wdf) {
  int i = blockIdx.x * 256 + threadIdx.x;
  if (i < 73728) { wfrag_one(w1, wf1, i, 64, 128, 4); return; }
  i -= 73728;
  if (i < 36864) { wfrag_one(wm1, wfm1, i, 64, 64, 4); return; }
  i -= 36864;
  if (i < 36864) { wfrag_one(wm2, wfm2, i, 64, 64, 4); return; }
  i -= 36864;
  if (i < 46080) { wfrag_one(wm3, wfm3, i, 72, 64, 5); return; }
  i -= 46080;
  if (i < 40960) wdcn_one(wdcn, wdf, i);
}

// ---- conv via LDS-staged 8x32 tile + 1px halo (10x34 rows, XOR-swizzled). ----
// oz-split: blockIdx.z (+ ozOff) selects which NFT-frag slice this block computes.
template<int CINB, int NFT, int CROW, bool LRELU>
__global__ __launch_bounds__(256, 3)
void conv_lds(const unsigned short* __restrict__ xt, const unsigned short* __restrict__ wfrag,
              const float* __restrict__ bias, unsigned short* __restrict__ out,
              int coutReal, int NFTOT, int ozOff) {
  __shared__ __align__(16) char xs[10 * 34 * 128];   // 43520 B
  const int tid = threadIdx.x;
  const int lane = tid & 63, wv = tid >> 6;
  const int l15 = lane & 15, lg = lane >> 4;
  const int b = blockIdx.y;
  const int ty = (blockIdx.x / 7) * 8, tx = (blockIdx.x % 7) * 32;
  const int ozBase = blockIdx.z * NFT + ozOff;
  const int CIN = CINB * 64;
  const unsigned short* xb = xt + (size_t)b * HW_ * CIN;

  f32x4 acc[4][NFT];
  #pragma unroll
  for (int mf = 0; mf < 4; ++mf)
    #pragma unroll
    for (int nf = 0; nf < NFT; ++nf) acc[mf][nf] = (f32x4){0.f, 0.f, 0.f, 0.f};

  #pragma unroll 1
  for (int cb2 = 0; cb2 < CINB; ++cb2) {
    if (cb2 > 0) __syncthreads();
    for (int ci = tid; ci < 2720; ci += 256) {
      const int ch = ci & 7;
      const int hp = ci >> 3;
      const int hr = hp / 34, hc = hp % 34;
      const int gy = ty + hr - 1, gx = tx + hc - 1;
      short8 v = (short8)0;
      if (((unsigned)gy < HH) & ((unsigned)gx < WW))
        v = *(const short8*)(xb + (size_t)(gy * WW + gx) * CIN + cb2 * 64 + ch * 8);
      *(short8*)(xs + hp * 128 + ((ch * 16) ^ ((hc & 7) << 4))) = v;
    }
    __syncthreads();

    #pragma unroll 2
    for (int k = 0; k < 9; ++k) {
      const int ky = k / 3, kx = k % 3;
      #pragma unroll
      for (int cb = 0; cb < 2; ++cb) {
        short8 av[4];
        #pragma unroll
        for (int mf = 0; mf < 4; ++mf) {
          const int hr = 2 * wv + (mf >> 1) + ky;
          const int hc = (mf & 1) * 16 + l15 + kx;
          av[mf] = *(const short8*)(xs + (hr * 34 + hc) * 128
                                    + ((cb * 64 + lg * 16) ^ ((hc & 7) << 4)));
        }
        #pragma unroll
        for (int nf = 0; nf < NFT; ++nf) {
          const short8 bv = *(const short8*)(wfrag
              + ((size_t)((k * (CINB * 2) + cb2 * 2 + cb) * NFTOT + ozBase + nf)) * 512 + lane * 8);
          #pragma unroll
          for (int mf = 0; mf < 4; ++mf)
            acc[mf][nf] = __builtin_amdgcn_mfma_f32_16x16x32_bf16(av[mf], bv, acc[mf][nf], 0, 0, 0);
        }
      }
    }
  }

  unsigned short* ob = out + (size_t)b * HW_ * CROW;
  #pragma unroll
  for (int nf = 0; nf < NFT; ++nf) {
    const int o = (ozBase + nf) * 16 + l15;
    const bool ov = (o < coutReal);
    const float bz = ov ? bias[o] : 0.f;
    #pragma unroll
    for (int mf = 0; mf < 4; ++mf) {
      const int rr = ty + 2 * wv + (mf >> 1);
      #pragma unroll
      for (int r = 0; r < 4; ++r) {
        const int cc = tx + (mf & 1) * 16 + lg * 4 + r;
        float vv = acc[mf][nf][r] + bz;
        if (LRELU) vv = lrelu_f(vv);
        if (ov) ob[(size_t)(rr * WW + cc) * CROW + o] = f2bf(vv);
      }
    }
  }
}

// ---- DCN v6: LDS-staged halo sampling + packed-pair lerp (float2 / cvt_pk_bf16). ----
__global__ __launch_bounds__(256, 3)
void dcn_v6(const unsigned short* __restrict__ xnb,  // [B][HW][64] bf16
            const unsigned short* __restrict__ offt, // [B][HW][72] bf16
            const unsigned short* __restrict__ wdf,  // fragment-ordered [80 fids][512]
            const float* __restrict__ bias, float* __restrict__ out) {
  __shared__ __align__(16) char xs[12 * 24 * 128];   // 36864 B
  const int tid = threadIdx.x;
  const int w = tid >> 6, l = tid & 63;
  const int l15 = l & 15, lg = l >> 4;
  const int b = blockIdx.y;
  const int bx = blockIdx.x;
  const int swz = (bx & 7) * 56 + (bx >> 3);       // bijective: 448 = 8*56
  const int tx = (swz % 14) * 16;
  const int ty = (swz / 14) * 4;
  const int y = ty + w;
  const int x = tx + l15;
  const int p_img = y * WW + x;
  const unsigned short* xb = xnb + (size_t)b * HW_ * 64;

  // stage halo: rows [ty-4, ty+8), cols [tx-4, tx+20), zero-fill out-of-image
  for (int ci = tid; ci < 2304; ci += 256) {
    const int ch = ci & 7;
    const int pos = ci >> 3;
    const int r = pos / 24, c = pos % 24;
    const int gy = ty - 4 + r, gx = tx - 4 + c;
    short8 v = (short8)0;
    if (((unsigned)gy < HH) & ((unsigned)gx < WW))
      v = *(const short8*)(xb + (size_t)(gy * WW + gx) * 64 + ch * 8);
    *(short8*)(xs + pos * 128 + ((ch * 16) ^ (((r + c) & 7) << 4))) = v;
  }
  __syncthreads();

  const unsigned* od = (const unsigned*)(offt + ((size_t)b * HW_ + p_img) * 72);
  const int thalf = lg >> 1;
  const int cofs0 = (lg & 1) * 8;

  f32x4 acc[4];
  #pragma unroll
  for (int mf = 0; mf < 4; ++mf) acc[mf] = (f32x4){0.f, 0.f, 0.f, 0.f};

  #pragma unroll 1
  for (int g = 0; g < 4; ++g) {
    const int cofs = g * 16 + cofs0;
    const int chunkB = cofs * 2;
    #pragma unroll 1
    for (int s = 0; s < 5; ++s) {
      const int t = 2 * s + thalf;
      const bool live = (t < 9);
      const unsigned dpair = od[g * 9 + (live ? t : 0)];
      const float dy = bf2f((unsigned short)(dpair & 0xffff));
      const float dx = bf2f((unsigned short)(dpair >> 16));
      const float sy = dy + (float)(y - 1 + t / 3);
      const float sx = dx + (float)(x - 1 + t % 3);
      const float fy = floorf(sy);
      const float fx = floorf(sx);
      const int y0 = (int)fy;
      const int x0 = (int)fx;
      const float ay = sy - fy;
      const float ax = sx - fx;
      float w00 = (1.f - ay) * (1.f - ax);
      float w01 = (1.f - ay) * ax;
      float w10 = ay * (1.f - ax);
      float w11 = ay * ax;
      const bool vy0 = (y0 >= 0) & (y0 < HH);
      const bool vy1 = (y0 + 1 >= 0) & (y0 + 1 < HH);
      const bool vx0 = (x0 >= 0) & (x0 < WW);
      const bool vx1 = (x0 + 1 >= 0) & (x0 + 1 < WW);
      w00 = (vy0 & vx0) ? w00 : 0.f;
      w01 = (vy0 & vx1) ? w01 : 0.f;
      w10 = (vy1 & vx0) ? w10 : 0.f;
      w11 = (vy1 & vx1) ? w11 : 0.f;
      const int cy0 = min(max(y0, 0), HH - 1);
      const int cy1 = min(max(y0 + 1, 0), HH - 1);
      const int cx0 = min(max(x0, 0), WW - 1);
      const int cx1 = min(max(x0 + 1, 0), WW - 1);
      const int ry0 = cy0 - ty + 4, ry1 = cy1 - ty + 4;
      const int rx0 = cx0 - tx + 4, rx1 = cx1 - tx + 4;
      const bool inT = !live | (((unsigned)ry0 < 12u) & ((unsigned)ry1 < 12u)
                              & ((unsigned)rx0 < 24u) & ((unsigned)rx1 < 24u));
      short8 q00, q01, q10, q11;
      if (__all((int)inT)) {
        const int a00 = (ry0 * 24 + rx0) * 128 + (chunkB ^ (((ry0 + rx0) & 7) << 4));
        const int a01 = (ry0 * 24 + rx1) * 128 + (chunkB ^ (((ry0 + rx1) & 7) << 4));
        const int a10 = (ry1 * 24 + rx0) * 128 + (chunkB ^ (((ry1 + rx0) & 7) << 4));
        const int a11 = (ry1 * 24 + rx1) * 128 + (chunkB ^ (((ry1 + rx1) & 7) << 4));
        q00 = *(const short8*)(xs + a00);
        q01 = *(const short8*)(xs + a01);
        q10 = *(const short8*)(xs + a10);
        q11 = *(const short8*)(xs + a11);
      } else {
        q00 = *(const short8*)(xb + (size_t)(cy0 * WW + cx0) * 64 + cofs);
        q01 = *(const short8*)(xb + (size_t)(cy0 * WW + cx1) * 64 + cofs);
        q10 = *(const short8*)(xb + (size_t)(cy1 * WW + cx0) * 64 + cofs);
        q11 = *(const short8*)(xb + (size_t)(cy1 * WW + cx1) * 64 + cofs);
      }
      short8 pf = (short8)0;
      if (live) {
        const unsigned* u00 = (const unsigned*)&q00;
        const unsigned* u01 = (const unsigned*)&q01;
        const unsigned* u10 = (const unsigned*)&q10;
        const unsigned* u11 = (const unsigned*)&q11;
        unsigned pr[4];
        #pragma unroll
        for (int i = 0; i < 4; ++i) {
          // unpack 2 bf16 -> float2 (1 shl + 1 and each)
          float2v f00, f01, f10, f11;
          f00.x = asf(u00[i] << 16); f00.y = asf(u00[i] & 0xffff0000u);
          f01.x = asf(u01[i] << 16); f01.y = asf(u01[i] & 0xffff0000u);
          f10.x = asf(u10[i] << 16); f10.y = asf(u10[i] & 0xffff0000u);
          f11.x = asf(u11[i] << 16); f11.y = asf(u11[i] & 0xffff0000u);
          const float2v s2 = f00 * w00 + f01 * w01 + f10 * w10 + f11 * w11;
          unsigned pk;
          asm("v_cvt_pk_bf16_f32 %0, %1, %2" : "=v"(pk) : "v"(s2.x), "v"(s2.y));
          pr[i] = pk;
        }
        pf = *(const short8*)pr;
      }
      #pragma unroll
      for (int mf = 0; mf < 4; ++mf) {
        const short8 wf = *(const short8*)(wdf + ((size_t)((g * 5 + s) * 4 + mf)) * 512 + l * 8);
        acc[mf] = __builtin_amdgcn_mfma_f32_16x16x32_bf16(wf, pf, acc[mf], 0, 0, 0);
      }
    }
  }

  float* ob = out + (size_t)b * 64 * HW_;
  #pragma unroll
  for (int mf = 0; mf < 4; ++mf) {
    #pragma unroll
    for (int r = 0; r < 4; ++r) {
      const int o = mf * 16 + lg * 4 + r;
      ob[(size_t)o * HW_ + p_img] = lrelu_f(acc[mf][r] + bias[o]);
    }
  }
}

extern "C" void kernel_launch(void* const* d_in, const int* in_sizes, int n_in,
                              void* d_out, int out_size, void* d_ws, size_t ws_size,
                              hipStream_t stream) {
  const float* nbr   = (const float*)d_in[0];
  const float* ref   = (const float*)d_in[1];
  const float* w_co1 = (const float*)d_in[2];
  const float* b_co1 = (const float*)d_in[3];
  const float* w_m1  = (const float*)d_in[4];
  const float* b_m1  = (const float*)d_in[5];
  const float* w_m2  = (const float*)d_in[6];
  const float* b_m2  = (const float*)d_in[7];
  const float* w_m3  = (const float*)d_in[8];
  const float* b_m3  = (const float*)d_in[9];
  const float* w_dcn = (const float*)d_in[10];
  const float* b_dcn = (const float*)d_in[11];
  float* out = (float*)d_out;

  char* ws = (char*)d_ws;
  unsigned short* xnb   = (unsigned short*)(ws);
  unsigned short* x1t   = (unsigned short*)(ws + 14680064);
  unsigned short* m1t   = (unsigned short*)(ws + 14680064);   // alias (after conv1)
  unsigned short* m2t   = (unsigned short*)(ws + 29360128);   // alias
  unsigned short* featt = (unsigned short*)(ws + 44040192);
  unsigned short* offt  = (unsigned short*)(ws + 44040192);   // alias (after m1)
  char* wbase = ws + 60555264;
  unsigned short* wf1  = (unsigned short*)(wbase);            // 147456
  unsigned short* wfm1 = (unsigned short*)(wbase + 147456);   // 73728
  unsigned short* wfm2 = (unsigned short*)(wbase + 221184);   // 73728
  unsigned short* wfm3 = (unsigned short*)(wbase + 294912);   // 92160
  unsigned short* wdf  = (unsigned short*)(wbase + 387072);   // 81920

  dim3 blk(256);
  prep_weights<<<dim3(916), blk, 0, stream>>>(w_co1, w_m1, w_m2, w_m3, w_dcn,
                                              wf1, wfm1, wfm2, wfm3, wdf);
  prep_xt<<<dim3(448, 4), blk, 0, stream>>>(nbr, ref, x1t, xnb);

  conv_lds<2, 2, 64, true ><<<dim3(112, 4, 2), blk, 0, stream>>>(x1t,   wf1,  b_co1, featt, 64, 4, 0);
  conv_lds<1, 2, 64, true ><<<dim3(112, 4, 2), blk, 0, stream>>>(featt, wfm1, b_m1,  m1t,   64, 4, 0);
  conv_lds<1, 2, 64, true ><<<dim3(112, 4, 2), blk, 0, stream>>>(m1t,   wfm2, b_m2,  m2t,   64, 4, 0);
  conv_lds<1, 3, 72, false><<<dim3(112, 4, 1), blk, 0, stream>>>(m2t,   wfm3, b_m3,  offt,  72, 5, 0);
  conv_lds<1, 2, 72, false><<<dim3(112, 4, 1), blk, 0, stream>>>(m2t,   wfm3, b_m3,  offt,  72, 5, 3);
  dcn_v6<<<dim3(448, 4), blk, 0, stream>>>(xnb, offt, wdf, b_dcn, out);
}

// Round 12
// 197.490 us; speedup vs baseline: 2.1377x; 1.0060x over previous
//
#include <hip/hip_runtime.h>

#define HH 128
#define WW 224
#define HW_ (HH * WW)   // 28672

typedef short short8 __attribute__((ext_vector_type(8)));
typedef float f32x4 __attribute__((ext_vector_type(4)));
typedef float float2v __attribute__((ext_vector_type(2)));

__device__ __forceinline__ float lrelu_f(float v) { return v >= 0.f ? v : 0.1f * v; }

__device__ __forceinline__ unsigned short f2bf(float f) {
  union { float f; unsigned u; } x; x.f = f;
  unsigned r = x.u + 0x7fff + ((x.u >> 16) & 1);   // RNE
  return (unsigned short)(r >> 16);
}
__device__ __forceinline__ float bf2f(unsigned short u) {
  union { unsigned u; float f; } x; x.u = ((unsigned)u) << 16; return x.f;
}
__device__ __forceinline__ float asf(unsigned u) {
  union { unsigned u; float f; } x; x.u = u; return x.f;
}

// ---- prep: concat(nbr,ref) -> x1t[b][p][128] bf16; also xnb[b][p][64] (nbr only) ----
__global__ __launch_bounds__(256)
void prep_xt(const float* __restrict__ nbr, const float* __restrict__ ref,
             unsigned short* __restrict__ xt, unsigned short* __restrict__ xnb) {
  const int lane = threadIdx.x & 63;
  const int q = threadIdx.x >> 6;
  const int p = blockIdx.x * 64 + lane;
  const int b = blockIdx.y;
  const int c0 = q * 32;
  const float* src = (c0 < 64) ? (nbr + ((size_t)b * 64 + c0) * HW_)
                               : (ref + ((size_t)b * 64 + (c0 - 64)) * HW_);
  unsigned short tmp[32];
  #pragma unroll
  for (int i = 0; i < 32; ++i) tmp[i] = f2bf(src[(size_t)i * HW_ + p]);
  unsigned short* dst = xt + ((size_t)b * HW_ + p) * 128 + c0;
  #pragma unroll
  for (int i = 0; i < 4; ++i)
    *(short8*)(dst + i * 8) = *(const short8*)(tmp + i * 8);
  if (c0 < 64) {
    unsigned short* dst2 = xnb + ((size_t)b * HW_ + p) * 64 + c0;
    #pragma unroll
    for (int i = 0; i < 4; ++i)
      *(short8*)(dst2 + i * 8) = *(const short8*)(tmp + i * 8);
  }
}

// ---- device helpers for weight conversion ----
__device__ __forceinline__ void wfrag_one(const float* __restrict__ w,
                                          unsigned short* __restrict__ wt,
                                          int i, int O, int C, int NFT) {
  const int CB = C / 32;
  const int j = i & 7;
  const int lane = (i >> 3) & 63;
  const int fid = i >> 9;
  const int nfg = fid % NFT;
  const int kcb = fid / NFT;
  const int cb = kcb % CB;
  const int k = kcb / CB;
  const int o = nfg * 16 + (lane & 15);
  const int c = cb * 32 + (lane >> 4) * 8 + j;
  float v = (o < O) ? w[((size_t)o * C + c) * 9 + k] : 0.f;
  wt[i] = f2bf(v);
}
__device__ __forceinline__ void wdcn_one(const float* __restrict__ w,
                                         unsigned short* __restrict__ wt, int i) {
  const int j = i & 7;
  const int lane = (i >> 3) & 63;
  const int fid = i >> 9;
  const int mf = fid & 3;
  const int s = (fid >> 2) % 5;
  const int g = fid / 20;
  const int l15 = lane & 15, lg = lane >> 4;
  const int o = mf * 16 + l15;
  const int t = 2 * s + (lg >> 1);
  const int c = g * 16 + (lg & 1) * 8 + j;
  float v = (t < 9) ? w[((size_t)o * 64 + c) * 9 + t] : 0.f;
  wt[i] = f2bf(v);
}

// ---- all weight preps merged into one kernel ----
__global__ void prep_weights(const float* __restrict__ w1, const float* __restrict__ wm1,
                             const float* __restrict__ wm2, const float* __restrict__ wm3,
                             const float* __restrict__ wdcn,
                             unsigned short* __restrict__ wf1, unsigned short* __restrict__ wfm1,
                             unsigned short* __restrict__ wfm2, unsigned short* __restrict__ wfm3,
                             unsigned short* __restrict__ wdf) {
  int i = blockIdx.x * 256 + threadIdx.x;
  if (i < 73728) { wfrag_one(w1, wf1, i, 64, 128, 4); return; }
  i -= 73728;
  if (i < 36864) { wfrag_one(wm1, wfm1, i, 64, 64, 4); return; }
  i -= 36864;
  if (i < 36864) { wfrag_one(wm2, wfm2, i, 64, 64, 4); return; }
  i -= 36864;
  if (i < 46080) { wfrag_one(wm3, wfm3, i, 72, 64, 5); return; }
  i -= 46080;
  if (i < 40960) wdcn_one(wdcn, wdf, i);
}

// ---- conv via LDS-staged 8x32 tile + 1px halo (10x34 rows, XOR-swizzled). ----
// NOTE: launch_bounds min-waves must stay at 2 (128 VGPR cap). 3 forced an ~85-VGPR
// cap -> scratch spills in the inner loop (rounds 6-11 conv slowness).
template<int CINB, int NFT, int CROW, bool LRELU>
__global__ __launch_bounds__(256, 2)
void conv_lds(const unsigned short* __restrict__ xt, const unsigned short* __restrict__ wfrag,
              const float* __restrict__ bias, unsigned short* __restrict__ out,
              int coutReal, int NFTOT, int ozOff) {
  __shared__ __align__(16) char xs[10 * 34 * 128];   // 43520 B
  const int tid = threadIdx.x;
  const int lane = tid & 63, wv = tid >> 6;
  const int l15 = lane & 15, lg = lane >> 4;
  const int b = blockIdx.y;
  const int ty = (blockIdx.x / 7) * 8, tx = (blockIdx.x % 7) * 32;
  const int ozBase = blockIdx.z * NFT + ozOff;
  const int CIN = CINB * 64;
  const unsigned short* xb = xt + (size_t)b * HW_ * CIN;

  f32x4 acc[4][NFT];
  #pragma unroll
  for (int mf = 0; mf < 4; ++mf)
    #pragma unroll
    for (int nf = 0; nf < NFT; ++nf) acc[mf][nf] = (f32x4){0.f, 0.f, 0.f, 0.f};

  #pragma unroll 1
  for (int cb2 = 0; cb2 < CINB; ++cb2) {
    if (cb2 > 0) __syncthreads();
    for (int ci = tid; ci < 2720; ci += 256) {
      const int ch = ci & 7;
      const int hp = ci >> 3;
      const int hr = hp / 34, hc = hp % 34;
      const int gy = ty + hr - 1, gx = tx + hc - 1;
      short8 v = (short8)0;
      if (((unsigned)gy < HH) & ((unsigned)gx < WW))
        v = *(const short8*)(xb + (size_t)(gy * WW + gx) * CIN + cb2 * 64 + ch * 8);
      *(short8*)(xs + hp * 128 + ((ch * 16) ^ ((hc & 7) << 4))) = v;
    }
    __syncthreads();

    #pragma unroll
    for (int k = 0; k < 9; ++k) {
      const int ky = k / 3, kx = k % 3;   // compile-time after full unroll
      #pragma unroll
      for (int cb = 0; cb < 2; ++cb) {
        short8 av[4];
        #pragma unroll
        for (int mf = 0; mf < 4; ++mf) {
          const int hr = 2 * wv + (mf >> 1) + ky;
          const int hc = (mf & 1) * 16 + l15 + kx;
          av[mf] = *(const short8*)(xs + (hr * 34 + hc) * 128
                                    + ((cb * 64 + lg * 16) ^ ((hc & 7) << 4)));
        }
        #pragma unroll
        for (int nf = 0; nf < NFT; ++nf) {
          const short8 bv = *(const short8*)(wfrag
              + ((size_t)((k * (CINB * 2) + cb2 * 2 + cb) * NFTOT + ozBase + nf)) * 512 + lane * 8);
          #pragma unroll
          for (int mf = 0; mf < 4; ++mf)
            acc[mf][nf] = __builtin_amdgcn_mfma_f32_16x16x32_bf16(av[mf], bv, acc[mf][nf], 0, 0, 0);
        }
      }
    }
  }

  unsigned short* ob = out + (size_t)b * HW_ * CROW;
  #pragma unroll
  for (int nf = 0; nf < NFT; ++nf) {
    const int o = (ozBase + nf) * 16 + l15;
    const bool ov = (o < coutReal);
    const float bz = ov ? bias[o] : 0.f;
    #pragma unroll
    for (int mf = 0; mf < 4; ++mf) {
      const int rr = ty + 2 * wv + (mf >> 1);
      #pragma unroll
      for (int r = 0; r < 4; ++r) {
        const int cc = tx + (mf & 1) * 16 + lg * 4 + r;
        float vv = acc[mf][nf][r] + bz;
        if (LRELU) vv = lrelu_f(vv);
        if (ov) ob[(size_t)(rr * WW + cc) * CROW + o] = f2bf(vv);
      }
    }
  }
}

// ---- DCN v6: LDS-staged halo sampling + packed-pair lerp (float2 / cvt_pk_bf16). ----
__global__ __launch_bounds__(256, 2)
void dcn_v6(const unsigned short* __restrict__ xnb,  // [B][HW][64] bf16
            const unsigned short* __restrict__ offt, // [B][HW][72] bf16
            const unsigned short* __restrict__ wdf,  // fragment-ordered [80 fids][512]
            const float* __restrict__ bias, float* __restrict__ out) {
  __shared__ __align__(16) char xs[12 * 24 * 128];   // 36864 B
  const int tid = threadIdx.x;
  const int w = tid >> 6, l = tid & 63;
  const int l15 = l & 15, lg = l >> 4;
  const int b = blockIdx.y;
  const int bx = blockIdx.x;
  const int swz = (bx & 7) * 56 + (bx >> 3);       // bijective: 448 = 8*56
  const int tx = (swz % 14) * 16;
  const int ty = (swz / 14) * 4;
  const int y = ty + w;
  const int x = tx + l15;
  const int p_img = y * WW + x;
  const unsigned short* xb = xnb + (size_t)b * HW_ * 64;

  for (int ci = tid; ci < 2304; ci += 256) {
    const int ch = ci & 7;
    const int pos = ci >> 3;
    const int r = pos / 24, c = pos % 24;
    const int gy = ty - 4 + r, gx = tx - 4 + c;
    short8 v = (short8)0;
    if (((unsigned)gy < HH) & ((unsigned)gx < WW))
      v = *(const short8*)(xb + (size_t)(gy * WW + gx) * 64 + ch * 8);
    *(short8*)(xs + pos * 128 + ((ch * 16) ^ (((r + c) & 7) << 4))) = v;
  }
  __syncthreads();

  const unsigned* od = (const unsigned*)(offt + ((size_t)b * HW_ + p_img) * 72);
  const int thalf = lg >> 1;
  const int cofs0 = (lg & 1) * 8;

  f32x4 acc[4];
  #pragma unroll
  for (int mf = 0; mf < 4; ++mf) acc[mf] = (f32x4){0.f, 0.f, 0.f, 0.f};

  #pragma unroll 1
  for (int g = 0; g < 4; ++g) {
    const int cofs = g * 16 + cofs0;
    const int chunkB = cofs * 2;
    #pragma unroll 1
    for (int s = 0; s < 5; ++s) {
      const int t = 2 * s + thalf;
      const bool live = (t < 9);
      const unsigned dpair = od[g * 9 + (live ? t : 0)];
      const float dy = bf2f((unsigned short)(dpair & 0xffff));
      const float dx = bf2f((unsigned short)(dpair >> 16));
      const float sy = dy + (float)(y - 1 + t / 3);
      const float sx = dx + (float)(x - 1 + t % 3);
      const float fy = floorf(sy);
      const float fx = floorf(sx);
      const int y0 = (int)fy;
      const int x0 = (int)fx;
      const float ay = sy - fy;
      const float ax = sx - fx;
      float w00 = (1.f - ay) * (1.f - ax);
      float w01 = (1.f - ay) * ax;
      float w10 = ay * (1.f - ax);
      float w11 = ay * ax;
      const bool vy0 = (y0 >= 0) & (y0 < HH);
      const bool vy1 = (y0 + 1 >= 0) & (y0 + 1 < HH);
      const bool vx0 = (x0 >= 0) & (x0 < WW);
      const bool vx1 = (x0 + 1 >= 0) & (x0 + 1 < WW);
      w00 = (vy0 & vx0) ? w00 : 0.f;
      w01 = (vy0 & vx1) ? w01 : 0.f;
      w10 = (vy1 & vx0) ? w10 : 0.f;
      w11 = (vy1 & vx1) ? w11 : 0.f;
      const int cy0 = min(max(y0, 0), HH - 1);
      const int cy1 = min(max(y0 + 1, 0), HH - 1);
      const int cx0 = min(max(x0, 0), WW - 1);
      const int cx1 = min(max(x0 + 1, 0), WW - 1);
      const int ry0 = cy0 - ty + 4, ry1 = cy1 - ty + 4;
      const int rx0 = cx0 - tx + 4, rx1 = cx1 - tx + 4;
      const bool inT = !live | (((unsigned)ry0 < 12u) & ((unsigned)ry1 < 12u)
                              & ((unsigned)rx0 < 24u) & ((unsigned)rx1 < 24u));
      short8 q00, q01, q10, q11;
      if (__all((int)inT)) {
        const int a00 = (ry0 * 24 + rx0) * 128 + (chunkB ^ (((ry0 + rx0) & 7) << 4));
        const int a01 = (ry0 * 24 + rx1) * 128 + (chunkB ^ (((ry0 + rx1) & 7) << 4));
        const int a10 = (ry1 * 24 + rx0) * 128 + (chunkB ^ (((ry1 + rx0) & 7) << 4));
        const int a11 = (ry1 * 24 + rx1) * 128 + (chunkB ^ (((ry1 + rx1) & 7) << 4));
        q00 = *(const short8*)(xs + a00);
        q01 = *(const short8*)(xs + a01);
        q10 = *(const short8*)(xs + a10);
        q11 = *(const short8*)(xs + a11);
      } else {
        q00 = *(const short8*)(xb + (size_t)(cy0 * WW + cx0) * 64 + cofs);
        q01 = *(const short8*)(xb + (size_t)(cy0 * WW + cx1) * 64 + cofs);
        q10 = *(const short8*)(xb + (size_t)(cy1 * WW + cx0) * 64 + cofs);
        q11 = *(const short8*)(xb + (size_t)(cy1 * WW + cx1) * 64 + cofs);
      }
      short8 pf = (short8)0;
      if (live) {
        const unsigned* u00 = (const unsigned*)&q00;
        const unsigned* u01 = (const unsigned*)&q01;
        const unsigned* u10 = (const unsigned*)&q10;
        const unsigned* u11 = (const unsigned*)&q11;
        unsigned pr[4];
        #pragma unroll
        for (int i = 0; i < 4; ++i) {
          float2v f00, f01, f10, f11;
          f00.x = asf(u00[i] << 16); f00.y = asf(u00[i] & 0xffff0000u);
          f01.x = asf(u01[i] << 16); f01.y = asf(u01[i] & 0xffff0000u);
          f10.x = asf(u10[i] << 16); f10.y = asf(u10[i] & 0xffff0000u);
          f11.x = asf(u11[i] << 16); f11.y = asf(u11[i] & 0xffff0000u);
          const float2v s2 = f00 * w00 + f01 * w01 + f10 * w10 + f11 * w11;
          unsigned pk;
          asm("v_cvt_pk_bf16_f32 %0, %1, %2" : "=v"(pk) : "v"(s2.x), "v"(s2.y));
          pr[i] = pk;
        }
        pf = *(const short8*)pr;
      }
      #pragma unroll
      for (int mf = 0; mf < 4; ++mf) {
        const short8 wf = *(const short8*)(wdf + ((size_t)((g * 5 + s) * 4 + mf)) * 512 + l * 8);
        acc[mf] = __builtin_amdgcn_mfma_f32_16x16x32_bf16(wf, pf, acc[mf], 0, 0, 0);
      }
    }
  }

  float* ob = out + (size_t)b * 64 * HW_;
  #pragma unroll
  for (int mf = 0; mf < 4; ++mf) {
    #pragma unroll
    for (int r = 0; r < 4; ++r) {
      const int o = mf * 16 + lg * 4 + r;
      ob[(size_t)o * HW_ + p_img] = lrelu_f(acc[mf][r] + bias[o]);
    }
  }
}

extern "C" void kernel_launch(void* const* d_in, const int* in_sizes, int n_in,
                              void* d_out, int out_size, void* d_ws, size_t ws_size,
                              hipStream_t stream) {
  const float* nbr   = (const float*)d_in[0];
  const float* ref   = (const float*)d_in[1];
  const float* w_co1 = (const float*)d_in[2];
  const float* b_co1 = (const float*)d_in[3];
  const float* w_m1  = (const float*)d_in[4];
  const float* b_m1  = (const float*)d_in[5];
  const float* w_m2  = (const float*)d_in[6];
  const float* b_m2  = (const float*)d_in[7];
  const float* w_m3  = (const float*)d_in[8];
  const float* b_m3  = (const float*)d_in[9];
  const float* w_dcn = (const float*)d_in[10];
  const float* b_dcn = (const float*)d_in[11];
  float* out = (float*)d_out;

  char* ws = (char*)d_ws;
  unsigned short* xnb   = (unsigned short*)(ws);
  unsigned short* x1t   = (unsigned short*)(ws + 14680064);
  unsigned short* m1t   = (unsigned short*)(ws + 14680064);   // alias (after conv1)
  unsigned short* m2t   = (unsigned short*)(ws + 29360128);   // alias
  unsigned short* featt = (unsigned short*)(ws + 44040192);
  unsigned short* offt  = (unsigned short*)(ws + 44040192);   // alias (after m1)
  char* wbase = ws + 60555264;
  unsigned short* wf1  = (unsigned short*)(wbase);            // 147456
  unsigned short* wfm1 = (unsigned short*)(wbase + 147456);   // 73728
  unsigned short* wfm2 = (unsigned short*)(wbase + 221184);   // 73728
  unsigned short* wfm3 = (unsigned short*)(wbase + 294912);   // 92160
  unsigned short* wdf  = (unsigned short*)(wbase + 387072);   // 81920

  dim3 blk(256);
  prep_weights<<<dim3(916), blk, 0, stream>>>(w_co1, w_m1, w_m2, w_m3, w_dcn,
                                              wf1, wfm1, wfm2, wfm3, wdf);
  prep_xt<<<dim3(448, 4), blk, 0, stream>>>(nbr, ref, x1t, xnb);

  conv_lds<2, 2, 64, true ><<<dim3(112, 4, 2), blk, 0, stream>>>(x1t,   wf1,  b_co1, featt, 64, 4, 0);
  conv_lds<1, 2, 64, true ><<<dim3(112, 4, 2), blk, 0, stream>>>(featt, wfm1, b_m1,  m1t,   64, 4, 0);
  conv_lds<1, 2, 64, true ><<<dim3(112, 4, 2), blk, 0, stream>>>(m1t,   wfm2, b_m2,  m2t,   64, 4, 0);
  conv_lds<1, 3, 72, false><<<dim3(112, 4, 1), blk, 0, stream>>>(m2t,   wfm3, b_m3,  offt,  72, 5, 0);
  conv_lds<1, 2, 72, false><<<dim3(112, 4, 1), blk, 0, stream>>>(m2t,   wfm3, b_m3,  offt,  72, 5, 3);
  dcn_v6<<<dim3(448, 4), blk, 0, stream>>>(xnb, offt, wdf, b_dcn, out);
}

// Round 13
// 174.175 us; speedup vs baseline: 2.4238x; 1.1339x over previous
//
#include <hip/hip_runtime.h>

#define HH 128
#define WW 224
#define HW_ (HH * WW)   // 28672

typedef short short8 __attribute__((ext_vector_type(8)));
typedef float f32x4 __attribute__((ext_vector_type(4)));
typedef float float2v __attribute__((ext_vector_type(2)));

__device__ __forceinline__ float lrelu_f(float v) { return v >= 0.f ? v : 0.1f * v; }

__device__ __forceinline__ unsigned short f2bf(float f) {
  union { float f; unsigned u; } x; x.f = f;
  unsigned r = x.u + 0x7fff + ((x.u >> 16) & 1);   // RNE
  return (unsigned short)(r >> 16);
}
__device__ __forceinline__ float bf2f(unsigned short u) {
  union { unsigned u; float f; } x; x.u = ((unsigned)u) << 16; return x.f;
}
__device__ __forceinline__ float asf(unsigned u) {
  union { unsigned u; float f; } x; x.u = u; return x.f;
}

// ---- prep: concat(nbr,ref) -> x1t[b][p][128] + xnb[b][p][64], LDS-transposed so
// global stores are contiguous (the old direct version stored 64 lines/instr). ----
__global__ __launch_bounds__(256)
void prep_xt(const float* __restrict__ nbr, const float* __restrict__ ref,
             unsigned short* __restrict__ xt, unsigned short* __restrict__ xnb) {
  __shared__ __align__(16) char ls[64 * 256];   // 64 px x 128 ch bf16 = 16 KB
  const int lane = threadIdx.x & 63;
  const int q = threadIdx.x >> 6;          // channel quarter (32 ch)
  const int p0 = blockIdx.x * 64;
  const int p = p0 + lane;
  const int b = blockIdx.y;
  const int c0 = q * 32;
  const float* src = (c0 < 64) ? (nbr + ((size_t)b * 64 + c0) * HW_)
                               : (ref + ((size_t)b * 64 + (c0 - 64)) * HW_);
  unsigned short tmp[32];
  #pragma unroll
  for (int i = 0; i < 32; ++i) tmp[i] = f2bf(src[(size_t)i * HW_ + p]);
  // LDS write: row = px(lane), bytes [c0*2, c0*2+64), XOR-swizzled 16B units
  #pragma unroll
  for (int j = 0; j < 4; ++j) {
    const int byte = (c0 * 2 + j * 16) ^ ((lane & 7) << 4);
    *(short8*)(ls + lane * 256 + byte) = *(const short8*)(tmp + j * 8);
  }
  __syncthreads();
  // x1t store: unit = px*16 + chunk; lanes cover consecutive chunks -> contiguous 1KB
  const int tid = threadIdx.x;
  unsigned short* dst = xt + ((size_t)b * HW_ + p0) * 128;
  #pragma unroll
  for (int j = 0; j < 4; ++j) {
    const int unit = tid * 4 + j;          // 0..1023
    const int px = unit >> 4, ck = unit & 15;
    const short8 v = *(const short8*)(ls + px * 256 + ((ck * 16) ^ ((px & 7) << 4)));
    *(short8*)(dst + (size_t)px * 128 + ck * 8) = v;
  }
  // xnb store (channels 0-63): unit = px*8 + chunk
  unsigned short* dst2 = xnb + ((size_t)b * HW_ + p0) * 64;
  #pragma unroll
  for (int j = 0; j < 2; ++j) {
    const int unit = tid * 2 + j;          // 0..511
    const int px = unit >> 3, ck = unit & 7;
    const short8 v = *(const short8*)(ls + px * 256 + ((ck * 16) ^ ((px & 7) << 4)));
    *(short8*)(dst2 + (size_t)px * 64 + ck * 8) = v;
  }
}

// ---- device helpers for weight conversion ----
__device__ __forceinline__ void wfrag_one(const float* __restrict__ w,
                                          unsigned short* __restrict__ wt,
                                          int i, int O, int C, int NFT) {
  const int CB = C / 32;
  const int j = i & 7;
  const int lane = (i >> 3) & 63;
  const int fid = i >> 9;
  const int nfg = fid % NFT;
  const int kcb = fid / NFT;
  const int cb = kcb % CB;
  const int k = kcb / CB;
  const int o = nfg * 16 + (lane & 15);
  const int c = cb * 32 + (lane >> 4) * 8 + j;
  float v = (o < O) ? w[((size_t)o * C + c) * 9 + k] : 0.f;
  wt[i] = f2bf(v);
}
__device__ __forceinline__ void wdcn_one(const float* __restrict__ w,
                                         unsigned short* __restrict__ wt, int i) {
  const int j = i & 7;
  const int lane = (i >> 3) & 63;
  const int fid = i >> 9;
  const int mf = fid & 3;
  const int s = (fid >> 2) % 5;
  const int g = fid / 20;
  const int l15 = lane & 15, lg = lane >> 4;
  const int o = mf * 16 + l15;
  const int t = 2 * s + (lg >> 1);
  const int c = g * 16 + (lg & 1) * 8 + j;
  float v = (t < 9) ? w[((size_t)o * 64 + c) * 9 + t] : 0.f;
  wt[i] = f2bf(v);
}

// ---- all weight preps merged into one kernel ----
__global__ void prep_weights(const float* __restrict__ w1, const float* __restrict__ wm1,
                             const float* __restrict__ wm2, const float* __restrict__ wm3,
                             const float* __restrict__ wdcn,
                             unsigned short* __restrict__ wf1, unsigned short* __restrict__ wfm1,
                             unsigned short* __restrict__ wfm2, unsigned short* __restrict__ wfm3,
                             unsigned short* __restrict__ wdf) {
  int i = blockIdx.x * 256 + threadIdx.x;
  if (i < 73728) { wfrag_one(w1, wf1, i, 64, 128, 4); return; }
  i -= 73728;
  if (i < 36864) { wfrag_one(wm1, wfm1, i, 64, 64, 4); return; }
  i -= 36864;
  if (i < 36864) { wfrag_one(wm2, wfm2, i, 64, 64, 4); return; }
  i -= 36864;
  if (i < 46080) { wfrag_one(wm3, wfm3, i, 72, 64, 5); return; }
  i -= 46080;
  if (i < 40960) wdcn_one(wdcn, wdf, i);
}

// ---- conv via LDS-staged 4x32 tile + 1px halo (6x34 rows, 26 KB, XOR-swizzled). ----
// Block: 256 thr = 4 waves; wave wv = row ty+wv x 32 cols (2 m-frags) x NFT*16 outputs.
// Grid: 224 tiles x batch. CINB = input 64-ch blocks, staged sequentially.
template<int CINB, int NFT, int CROW, bool LRELU>
__global__ __launch_bounds__(256, 2)
void conv_lds(const unsigned short* __restrict__ xt, const unsigned short* __restrict__ wfrag,
              const float* __restrict__ bias, unsigned short* __restrict__ out, int coutReal) {
  __shared__ __align__(16) char xs[6 * 34 * 128];   // 26112 B
  const int tid = threadIdx.x;
  const int lane = tid & 63, wv = tid >> 6;
  const int l15 = lane & 15, lg = lane >> 4;
  const int b = blockIdx.y;
  const int ty = (blockIdx.x / 7) * 4, tx = (blockIdx.x % 7) * 32;
  const int CIN = CINB * 64;
  const unsigned short* xb = xt + (size_t)b * HW_ * CIN;

  f32x4 acc[2][NFT];
  #pragma unroll
  for (int mf = 0; mf < 2; ++mf)
    #pragma unroll
    for (int nf = 0; nf < NFT; ++nf) acc[mf][nf] = (f32x4){0.f, 0.f, 0.f, 0.f};

  #pragma unroll 1
  for (int cb2 = 0; cb2 < CINB; ++cb2) {
    if (cb2 > 0) __syncthreads();
    // stage 6x34 px halo (64-ch slice): 1632 short8 units, coalesced, zero-fill OOB
    for (int ci = tid; ci < 1632; ci += 256) {
      const int ch = ci & 7;
      const int hp = ci >> 3;
      const int hr = hp / 34, hc = hp % 34;
      const int gy = ty + hr - 1, gx = tx + hc - 1;
      short8 v = (short8)0;
      if (((unsigned)gy < HH) & ((unsigned)gx < WW))
        v = *(const short8*)(xb + (size_t)(gy * WW + gx) * CIN + cb2 * 64 + ch * 8);
      *(short8*)(xs + hp * 128 + ((ch * 16) ^ ((hc & 7) << 4))) = v;
    }
    __syncthreads();

    #pragma unroll
    for (int k = 0; k < 9; ++k) {
      const int ky = k / 3, kx = k % 3;
      #pragma unroll
      for (int cb = 0; cb < 2; ++cb) {
        short8 av[2];
        #pragma unroll
        for (int mf = 0; mf < 2; ++mf) {
          const int hr = wv + ky;
          const int hc = mf * 16 + l15 + kx;
          av[mf] = *(const short8*)(xs + (hr * 34 + hc) * 128
                                    + ((cb * 64 + lg * 16) ^ ((hc & 7) << 4)));
        }
        #pragma unroll
        for (int nf = 0; nf < NFT; ++nf) {
          const short8 bv = *(const short8*)(wfrag
              + ((size_t)((k * (CINB * 2) + cb2 * 2 + cb) * NFT + nf)) * 512 + lane * 8);
          #pragma unroll
          for (int mf = 0; mf < 2; ++mf)
            acc[mf][nf] = __builtin_amdgcn_mfma_f32_16x16x32_bf16(av[mf], bv, acc[mf][nf], 0, 0, 0);
        }
      }
    }
  }

  unsigned short* ob = out + (size_t)b * HW_ * CROW;
  const int rr = ty + wv;
  #pragma unroll
  for (int nf = 0; nf < NFT; ++nf) {
    const int o = nf * 16 + l15;
    const bool ov = (o < coutReal);
    const float bz = ov ? bias[o] : 0.f;
    #pragma unroll
    for (int mf = 0; mf < 2; ++mf) {
      #pragma unroll
      for (int r = 0; r < 4; ++r) {
        const int cc = tx + mf * 16 + lg * 4 + r;
        float vv = acc[mf][nf][r] + bz;
        if (LRELU) vv = lrelu_f(vv);
        if (ov) ob[(size_t)(rr * WW + cc) * CROW + o] = f2bf(vv);
      }
    }
  }
}

// ---- DCN v6: LDS-staged halo sampling + packed-pair lerp (float2 / cvt_pk_bf16). ----
__global__ __launch_bounds__(256, 2)
void dcn_v6(const unsigned short* __restrict__ xnb,  // [B][HW][64] bf16
            const unsigned short* __restrict__ offt, // [B][HW][72] bf16
            const unsigned short* __restrict__ wdf,  // fragment-ordered [80 fids][512]
            const float* __restrict__ bias, float* __restrict__ out) {
  __shared__ __align__(16) char xs[12 * 24 * 128];   // 36864 B
  const int tid = threadIdx.x;
  const int w = tid >> 6, l = tid & 63;
  const int l15 = l & 15, lg = l >> 4;
  const int b = blockIdx.y;
  const int bx = blockIdx.x;
  const int swz = (bx & 7) * 56 + (bx >> 3);       // bijective: 448 = 8*56
  const int tx = (swz % 14) * 16;
  const int ty = (swz / 14) * 4;
  const int y = ty + w;
  const int x = tx + l15;
  const int p_img = y * WW + x;
  const unsigned short* xb = xnb + (size_t)b * HW_ * 64;

  for (int ci = tid; ci < 2304; ci += 256) {
    const int ch = ci & 7;
    const int pos = ci >> 3;
    const int r = pos / 24, c = pos % 24;
    const int gy = ty - 4 + r, gx = tx - 4 + c;
    short8 v = (short8)0;
    if (((unsigned)gy < HH) & ((unsigned)gx < WW))
      v = *(const short8*)(xb + (size_t)(gy * WW + gx) * 64 + ch * 8);
    *(short8*)(xs + pos * 128 + ((ch * 16) ^ (((r + c) & 7) << 4))) = v;
  }
  __syncthreads();

  const unsigned* od = (const unsigned*)(offt + ((size_t)b * HW_ + p_img) * 72);
  const int thalf = lg >> 1;
  const int cofs0 = (lg & 1) * 8;

  f32x4 acc[4];
  #pragma unroll
  for (int mf = 0; mf < 4; ++mf) acc[mf] = (f32x4){0.f, 0.f, 0.f, 0.f};

  #pragma unroll 1
  for (int g = 0; g < 4; ++g) {
    const int cofs = g * 16 + cofs0;
    const int chunkB = cofs * 2;
    #pragma unroll 1
    for (int s = 0; s < 5; ++s) {
      const int t = 2 * s + thalf;
      const bool live = (t < 9);
      const unsigned dpair = od[g * 9 + (live ? t : 0)];
      const float dy = bf2f((unsigned short)(dpair & 0xffff));
      const float dx = bf2f((unsigned short)(dpair >> 16));
      const float sy = dy + (float)(y - 1 + t / 3);
      const float sx = dx + (float)(x - 1 + t % 3);
      const float fy = floorf(sy);
      const float fx = floorf(sx);
      const int y0 = (int)fy;
      const int x0 = (int)fx;
      const float ay = sy - fy;
      const float ax = sx - fx;
      float w00 = (1.f - ay) * (1.f - ax);
      float w01 = (1.f - ay) * ax;
      float w10 = ay * (1.f - ax);
      float w11 = ay * ax;
      const bool vy0 = (y0 >= 0) & (y0 < HH);
      const bool vy1 = (y0 + 1 >= 0) & (y0 + 1 < HH);
      const bool vx0 = (x0 >= 0) & (x0 < WW);
      const bool vx1 = (x0 + 1 >= 0) & (x0 + 1 < WW);
      w00 = (vy0 & vx0) ? w00 : 0.f;
      w01 = (vy0 & vx1) ? w01 : 0.f;
      w10 = (vy1 & vx0) ? w10 : 0.f;
      w11 = (vy1 & vx1) ? w11 : 0.f;
      const int cy0 = min(max(y0, 0), HH - 1);
      const int cy1 = min(max(y0 + 1, 0), HH - 1);
      const int cx0 = min(max(x0, 0), WW - 1);
      const int cx1 = min(max(x0 + 1, 0), WW - 1);
      const int ry0 = cy0 - ty + 4, ry1 = cy1 - ty + 4;
      const int rx0 = cx0 - tx + 4, rx1 = cx1 - tx + 4;
      const bool inT = !live | (((unsigned)ry0 < 12u) & ((unsigned)ry1 < 12u)
                              & ((unsigned)rx0 < 24u) & ((unsigned)rx1 < 24u));
      short8 q00, q01, q10, q11;
      if (__all((int)inT)) {
        const int a00 = (ry0 * 24 + rx0) * 128 + (chunkB ^ (((ry0 + rx0) & 7) << 4));
        const int a01 = (ry0 * 24 + rx1) * 128 + (chunkB ^ (((ry0 + rx1) & 7) << 4));
        const int a10 = (ry1 * 24 + rx0) * 128 + (chunkB ^ (((ry1 + rx0) & 7) << 4));
        const int a11 = (ry1 * 24 + rx1) * 128 + (chunkB ^ (((ry1 + rx1) & 7) << 4));
        q00 = *(const short8*)(xs + a00);
        q01 = *(const short8*)(xs + a01);
        q10 = *(const short8*)(xs + a10);
        q11 = *(const short8*)(xs + a11);
      } else {
        q00 = *(const short8*)(xb + (size_t)(cy0 * WW + cx0) * 64 + cofs);
        q01 = *(const short8*)(xb + (size_t)(cy0 * WW + cx1) * 64 + cofs);
        q10 = *(const short8*)(xb + (size_t)(cy1 * WW + cx0) * 64 + cofs);
        q11 = *(const short8*)(xb + (size_t)(cy1 * WW + cx1) * 64 + cofs);
      }
      short8 pf = (short8)0;
      if (live) {
        const unsigned* u00 = (const unsigned*)&q00;
        const unsigned* u01 = (const unsigned*)&q01;
        const unsigned* u10 = (const unsigned*)&q10;
        const unsigned* u11 = (const unsigned*)&q11;
        unsigned pr[4];
        #pragma unroll
        for (int i = 0; i < 4; ++i) {
          float2v f00, f01, f10, f11;
          f00.x = asf(u00[i] << 16); f00.y = asf(u00[i] & 0xffff0000u);
          f01.x = asf(u01[i] << 16); f01.y = asf(u01[i] & 0xffff0000u);
          f10.x = asf(u10[i] << 16); f10.y = asf(u10[i] & 0xffff0000u);
          f11.x = asf(u11[i] << 16); f11.y = asf(u11[i] & 0xffff0000u);
          const float2v s2 = f00 * w00 + f01 * w01 + f10 * w10 + f11 * w11;
          unsigned pk;
          asm("v_cvt_pk_bf16_f32 %0, %1, %2" : "=v"(pk) : "v"(s2.x), "v"(s2.y));
          pr[i] = pk;
        }
        pf = *(const short8*)pr;
      }
      #pragma unroll
      for (int mf = 0; mf < 4; ++mf) {
        const short8 wf = *(const short8*)(wdf + ((size_t)((g * 5 + s) * 4 + mf)) * 512 + l * 8);
        acc[mf] = __builtin_amdgcn_mfma_f32_16x16x32_bf16(wf, pf, acc[mf], 0, 0, 0);
      }
    }
  }

  float* ob = out + (size_t)b * 64 * HW_;
  #pragma unroll
  for (int mf = 0; mf < 4; ++mf) {
    #pragma unroll
    for (int r = 0; r < 4; ++r) {
      const int o = mf * 16 + lg * 4 + r;
      ob[(size_t)o * HW_ + p_img] = lrelu_f(acc[mf][r] + bias[o]);
    }
  }
}

extern "C" void kernel_launch(void* const* d_in, const int* in_sizes, int n_in,
                              void* d_out, int out_size, void* d_ws, size_t ws_size,
                              hipStream_t stream) {
  const float* nbr   = (const float*)d_in[0];
  const float* ref   = (const float*)d_in[1];
  const float* w_co1 = (const float*)d_in[2];
  const float* b_co1 = (const float*)d_in[3];
  const float* w_m1  = (const float*)d_in[4];
  const float* b_m1  = (const float*)d_in[5];
  const float* w_m2  = (const float*)d_in[6];
  const float* b_m2  = (const float*)d_in[7];
  const float* w_m3  = (const float*)d_in[8];
  const float* b_m3  = (const float*)d_in[9];
  const float* w_dcn = (const float*)d_in[10];
  const float* b_dcn = (const float*)d_in[11];
  float* out = (float*)d_out;

  char* ws = (char*)d_ws;
  unsigned short* xnb   = (unsigned short*)(ws);
  unsigned short* x1t   = (unsigned short*)(ws + 14680064);
  unsigned short* m1t   = (unsigned short*)(ws + 14680064);   // alias (after conv1)
  unsigned short* m2t   = (unsigned short*)(ws + 29360128);   // alias
  unsigned short* featt = (unsigned short*)(ws + 44040192);
  unsigned short* offt  = (unsigned short*)(ws + 44040192);   // alias (after m1)
  char* wbase = ws + 60555264;
  unsigned short* wf1  = (unsigned short*)(wbase);            // 147456
  unsigned short* wfm1 = (unsigned short*)(wbase + 147456);   // 73728
  unsigned short* wfm2 = (unsigned short*)(wbase + 221184);   // 73728
  unsigned short* wfm3 = (unsigned short*)(wbase + 294912);   // 92160
  unsigned short* wdf  = (unsigned short*)(wbase + 387072);   // 81920

  dim3 blk(256);
  prep_weights<<<dim3(916), blk, 0, stream>>>(w_co1, w_m1, w_m2, w_m3, w_dcn,
                                              wf1, wfm1, wfm2, wfm3, wdf);
  prep_xt<<<dim3(448, 4), blk, 0, stream>>>(nbr, ref, x1t, xnb);

  conv_lds<2, 4, 64, true ><<<dim3(224, 4), blk, 0, stream>>>(x1t,   wf1,  b_co1, featt, 64);
  conv_lds<1, 4, 64, true ><<<dim3(224, 4), blk, 0, stream>>>(featt, wfm1, b_m1,  m1t,   64);
  conv_lds<1, 4, 64, true ><<<dim3(224, 4), blk, 0, stream>>>(m1t,   wfm2, b_m2,  m2t,   64);
  conv_lds<1, 5, 72, false><<<dim3(224, 4), blk, 0, stream>>>(m2t,   wfm3, b_m3,  offt,  72);
  dcn_v6<<<dim3(448, 4), blk, 0, stream>>>(xnb, offt, wdf, b_dcn, out);
}

// Round 14
// 167.087 us; speedup vs baseline: 2.5266x; 1.0424x over previous
//
#include <hip/hip_runtime.h>

#define HH 128
#define WW 224
#define HW_ (HH * WW)   // 28672

typedef short short8 __attribute__((ext_vector_type(8)));
typedef float f32x4 __attribute__((ext_vector_type(4)));
typedef float float2v __attribute__((ext_vector_type(2)));

__device__ __forceinline__ float lrelu_f(float v) { return v >= 0.f ? v : 0.1f * v; }

__device__ __forceinline__ unsigned short f2bf(float f) {
  union { float f; unsigned u; } x; x.f = f;
  unsigned r = x.u + 0x7fff + ((x.u >> 16) & 1);   // RNE
  return (unsigned short)(r >> 16);
}
__device__ __forceinline__ float bf2f(unsigned short u) {
  union { unsigned u; float f; } x; x.u = ((unsigned)u) << 16; return x.f;
}
__device__ __forceinline__ float asf(unsigned u) {
  union { unsigned u; float f; } x; x.u = u; return x.f;
}

// ---- weight-conversion helpers ----
__device__ __forceinline__ void wfrag_one(const float* __restrict__ w,
                                          unsigned short* __restrict__ wt,
                                          int i, int O, int C, int NFT) {
  const int CB = C / 32;
  const int j = i & 7;
  const int lane = (i >> 3) & 63;
  const int fid = i >> 9;
  const int nfg = fid % NFT;
  const int kcb = fid / NFT;
  const int cb = kcb % CB;
  const int k = kcb / CB;
  const int o = nfg * 16 + (lane & 15);
  const int c = cb * 32 + (lane >> 4) * 8 + j;
  float v = (o < O) ? w[((size_t)o * C + c) * 9 + k] : 0.f;
  wt[i] = f2bf(v);
}
__device__ __forceinline__ void wdcn_one(const float* __restrict__ w,
                                         unsigned short* __restrict__ wt, int i) {
  const int j = i & 7;
  const int lane = (i >> 3) & 63;
  const int fid = i >> 9;
  const int mf = fid & 3;
  const int s = (fid >> 2) % 5;
  const int g = fid / 20;
  const int l15 = lane & 15, lg = lane >> 4;
  const int o = mf * 16 + l15;
  const int t = 2 * s + (lg >> 1);
  const int c = g * 16 + (lg & 1) * 8 + j;
  float v = (t < 9) ? w[((size_t)o * 64 + c) * 9 + t] : 0.f;
  wt[i] = f2bf(v);
}

// ---- one prep launch: blocks [0,1792) transpose inputs; [1792,2708) convert weights ----
__global__ __launch_bounds__(256)
void prep_all(const float* __restrict__ nbr, const float* __restrict__ ref,
              const float* __restrict__ w1, const float* __restrict__ wm1,
              const float* __restrict__ wm2, const float* __restrict__ wm3,
              const float* __restrict__ wdcn,
              unsigned short* __restrict__ xt, unsigned short* __restrict__ xnb,
              unsigned short* __restrict__ wf1, unsigned short* __restrict__ wfm1,
              unsigned short* __restrict__ wfm2, unsigned short* __restrict__ wfm3,
              unsigned short* __restrict__ wdf) {
  __shared__ __align__(16) char ls[64 * 256];   // 16 KB (xt path only)
  if (blockIdx.x >= 1792) {
    int i = (blockIdx.x - 1792) * 256 + threadIdx.x;
    if (i < 73728) { wfrag_one(w1, wf1, i, 64, 128, 4); return; }
    i -= 73728;
    if (i < 36864) { wfrag_one(wm1, wfm1, i, 64, 64, 4); return; }
    i -= 36864;
    if (i < 36864) { wfrag_one(wm2, wfm2, i, 64, 64, 4); return; }
    i -= 36864;
    if (i < 46080) { wfrag_one(wm3, wfm3, i, 72, 64, 5); return; }
    i -= 46080;
    if (i < 40960) wdcn_one(wdcn, wdf, i);
    return;
  }
  const int lane = threadIdx.x & 63;
  const int q = threadIdx.x >> 6;          // channel quarter (32 ch)
  const int bxp = blockIdx.x % 448;
  const int b = blockIdx.x / 448;
  const int p0 = bxp * 64;
  const int p = p0 + lane;
  const int c0 = q * 32;
  const float* src = (c0 < 64) ? (nbr + ((size_t)b * 64 + c0) * HW_)
                               : (ref + ((size_t)b * 64 + (c0 - 64)) * HW_);
  unsigned short tmp[32];
  #pragma unroll
  for (int i = 0; i < 32; ++i) tmp[i] = f2bf(src[(size_t)i * HW_ + p]);
  #pragma unroll
  for (int j = 0; j < 4; ++j) {
    const int byte = (c0 * 2 + j * 16) ^ ((lane & 7) << 4);
    *(short8*)(ls + lane * 256 + byte) = *(const short8*)(tmp + j * 8);
  }
  __syncthreads();
  const int tid = threadIdx.x;
  unsigned short* dst = xt + ((size_t)b * HW_ + p0) * 128;
  #pragma unroll
  for (int j = 0; j < 4; ++j) {
    const int unit = tid * 4 + j;
    const int px = unit >> 4, ck = unit & 15;
    const short8 v = *(const short8*)(ls + px * 256 + ((ck * 16) ^ ((px & 7) << 4)));
    *(short8*)(dst + (size_t)px * 128 + ck * 8) = v;
  }
  unsigned short* dst2 = xnb + ((size_t)b * HW_ + p0) * 64;
  #pragma unroll
  for (int j = 0; j < 2; ++j) {
    const int unit = tid * 2 + j;
    const int px = unit >> 3, ck = unit & 7;
    const short8 v = *(const short8*)(ls + px * 256 + ((ck * 16) ^ ((px & 7) << 4)));
    *(short8*)(dst2 + (size_t)px * 64 + ck * 8) = v;
  }
}

// ---- conv, 8x32 tile (10x34 halo, 43.5 KB): wave = 2 rows x 32 cols (4 m-frags)
// x NFT*16 outputs -> 16 MFMA per 8 loads (2x the load-reuse of the 4x32 shape). ----
template<int CINB, int NFT, int CROW, bool LRELU>
__global__ __launch_bounds__(256, 2)
void conv_lds2(const unsigned short* __restrict__ xt, const unsigned short* __restrict__ wfrag,
               const float* __restrict__ bias, unsigned short* __restrict__ out, int coutReal) {
  __shared__ __align__(16) char xs[10 * 34 * 128];   // 43520 B
  const int tid = threadIdx.x;
  const int lane = tid & 63, wv = tid >> 6;
  const int l15 = lane & 15, lg = lane >> 4;
  const int b = blockIdx.y;
  const int ty = (blockIdx.x / 7) * 8, tx = (blockIdx.x % 7) * 32;
  const int CIN = CINB * 64;
  const unsigned short* xb = xt + (size_t)b * HW_ * CIN;

  f32x4 acc[4][NFT];
  #pragma unroll
  for (int mf = 0; mf < 4; ++mf)
    #pragma unroll
    for (int nf = 0; nf < NFT; ++nf) acc[mf][nf] = (f32x4){0.f, 0.f, 0.f, 0.f};

  #pragma unroll 1
  for (int cb2 = 0; cb2 < CINB; ++cb2) {
    if (cb2 > 0) __syncthreads();
    for (int ci = tid; ci < 2720; ci += 256) {
      const int ch = ci & 7;
      const int hp = ci >> 3;
      const int hr = hp / 34, hc = hp % 34;
      const int gy = ty + hr - 1, gx = tx + hc - 1;
      short8 v = (short8)0;
      if (((unsigned)gy < HH) & ((unsigned)gx < WW))
        v = *(const short8*)(xb + (size_t)(gy * WW + gx) * CIN + cb2 * 64 + ch * 8);
      *(short8*)(xs + hp * 128 + ((ch * 16) ^ ((hc & 7) << 4))) = v;
    }
    __syncthreads();

    #pragma unroll
    for (int k = 0; k < 9; ++k) {
      const int ky = k / 3, kx = k % 3;
      #pragma unroll
      for (int cb = 0; cb < 2; ++cb) {
        short8 av[4];
        #pragma unroll
        for (int mf = 0; mf < 4; ++mf) {
          const int hr = 2 * wv + (mf >> 1) + ky;
          const int hc = (mf & 1) * 16 + l15 + kx;
          av[mf] = *(const short8*)(xs + (hr * 34 + hc) * 128
                                    + ((cb * 64 + lg * 16) ^ ((hc & 7) << 4)));
        }
        #pragma unroll
        for (int nf = 0; nf < NFT; ++nf) {
          const short8 bv = *(const short8*)(wfrag
              + ((size_t)((k * (CINB * 2) + cb2 * 2 + cb) * NFT + nf)) * 512 + lane * 8);
          #pragma unroll
          for (int mf = 0; mf < 4; ++mf)
            acc[mf][nf] = __builtin_amdgcn_mfma_f32_16x16x32_bf16(av[mf], bv, acc[mf][nf], 0, 0, 0);
        }
      }
    }
  }

  unsigned short* ob = out + (size_t)b * HW_ * CROW;
  #pragma unroll
  for (int nf = 0; nf < NFT; ++nf) {
    const int o = nf * 16 + l15;
    const bool ov = (o < coutReal);
    const float bz = ov ? bias[o] : 0.f;
    #pragma unroll
    for (int mf = 0; mf < 4; ++mf) {
      const int rr = ty + 2 * wv + (mf >> 1);
      #pragma unroll
      for (int r = 0; r < 4; ++r) {
        const int cc = tx + (mf & 1) * 16 + lg * 4 + r;
        float vv = acc[mf][nf][r] + bz;
        if (LRELU) vv = lrelu_f(vv);
        if (ov) ob[(size_t)(rr * WW + cc) * CROW + o] = f2bf(vv);
      }
    }
  }
}

// ---- conv, 4x32 tile (6x34 halo, 26 KB) — used for m3 (NFT=5, acc fits). ----
template<int CINB, int NFT, int CROW, bool LRELU>
__global__ __launch_bounds__(256, 2)
void conv_lds(const unsigned short* __restrict__ xt, const unsigned short* __restrict__ wfrag,
              const float* __restrict__ bias, unsigned short* __restrict__ out, int coutReal) {
  __shared__ __align__(16) char xs[6 * 34 * 128];   // 26112 B
  const int tid = threadIdx.x;
  const int lane = tid & 63, wv = tid >> 6;
  const int l15 = lane & 15, lg = lane >> 4;
  const int b = blockIdx.y;
  const int ty = (blockIdx.x / 7) * 4, tx = (blockIdx.x % 7) * 32;
  const int CIN = CINB * 64;
  const unsigned short* xb = xt + (size_t)b * HW_ * CIN;

  f32x4 acc[2][NFT];
  #pragma unroll
  for (int mf = 0; mf < 2; ++mf)
    #pragma unroll
    for (int nf = 0; nf < NFT; ++nf) acc[mf][nf] = (f32x4){0.f, 0.f, 0.f, 0.f};

  #pragma unroll 1
  for (int cb2 = 0; cb2 < CINB; ++cb2) {
    if (cb2 > 0) __syncthreads();
    for (int ci = tid; ci < 1632; ci += 256) {
      const int ch = ci & 7;
      const int hp = ci >> 3;
      const int hr = hp / 34, hc = hp % 34;
      const int gy = ty + hr - 1, gx = tx + hc - 1;
      short8 v = (short8)0;
      if (((unsigned)gy < HH) & ((unsigned)gx < WW))
        v = *(const short8*)(xb + (size_t)(gy * WW + gx) * CIN + cb2 * 64 + ch * 8);
      *(short8*)(xs + hp * 128 + ((ch * 16) ^ ((hc & 7) << 4))) = v;
    }
    __syncthreads();

    #pragma unroll
    for (int k = 0; k < 9; ++k) {
      const int ky = k / 3, kx = k % 3;
      #pragma unroll
      for (int cb = 0; cb < 2; ++cb) {
        short8 av[2];
        #pragma unroll
        for (int mf = 0; mf < 2; ++mf) {
          const int hr = wv + ky;
          const int hc = mf * 16 + l15 + kx;
          av[mf] = *(const short8*)(xs + (hr * 34 + hc) * 128
                                    + ((cb * 64 + lg * 16) ^ ((hc & 7) << 4)));
        }
        #pragma unroll
        for (int nf = 0; nf < NFT; ++nf) {
          const short8 bv = *(const short8*)(wfrag
              + ((size_t)((k * (CINB * 2) + cb2 * 2 + cb) * NFT + nf)) * 512 + lane * 8);
          #pragma unroll
          for (int mf = 0; mf < 2; ++mf)
            acc[mf][nf] = __builtin_amdgcn_mfma_f32_16x16x32_bf16(av[mf], bv, acc[mf][nf], 0, 0, 0);
        }
      }
    }
  }

  unsigned short* ob = out + (size_t)b * HW_ * CROW;
  const int rr = ty + wv;
  #pragma unroll
  for (int nf = 0; nf < NFT; ++nf) {
    const int o = nf * 16 + l15;
    const bool ov = (o < coutReal);
    const float bz = ov ? bias[o] : 0.f;
    #pragma unroll
    for (int mf = 0; mf < 2; ++mf) {
      #pragma unroll
      for (int r = 0; r < 4; ++r) {
        const int cc = tx + mf * 16 + lg * 4 + r;
        float vv = acc[mf][nf][r] + bz;
        if (LRELU) vv = lrelu_f(vv);
        if (ov) ob[(size_t)(rr * WW + cc) * CROW + o] = f2bf(vv);
      }
    }
  }
}

// ---- DCN v7: LDS halo sampling; fast path has NO clamps/validity/weight-masking
// (halo is zero-filled outside image; w*0 = 0 matches the reference's masking). ----
__global__ __launch_bounds__(256, 2)
void dcn_v7(const unsigned short* __restrict__ xnb,  // [B][HW][64] bf16
            const unsigned short* __restrict__ offt, // [B][HW][72] bf16
            const unsigned short* __restrict__ wdf,  // fragment-ordered [80 fids][512]
            const float* __restrict__ bias, float* __restrict__ out) {
  __shared__ __align__(16) char xs[12 * 24 * 128];   // 36864 B
  const int tid = threadIdx.x;
  const int w = tid >> 6, l = tid & 63;
  const int l15 = l & 15, lg = l >> 4;
  const int b = blockIdx.y;
  const int bx = blockIdx.x;
  const int swz = (bx & 7) * 56 + (bx >> 3);       // bijective: 448 = 8*56
  const int tx = (swz % 14) * 16;
  const int ty = (swz / 14) * 4;
  const int y = ty + w;
  const int x = tx + l15;
  const int p_img = y * WW + x;
  const unsigned short* xb = xnb + (size_t)b * HW_ * 64;

  for (int ci = tid; ci < 2304; ci += 256) {
    const int ch = ci & 7;
    const int pos = ci >> 3;
    const int r = pos / 24, c = pos % 24;
    const int gy = ty - 4 + r, gx = tx - 4 + c;
    short8 v = (short8)0;
    if (((unsigned)gy < HH) & ((unsigned)gx < WW))
      v = *(const short8*)(xb + (size_t)(gy * WW + gx) * 64 + ch * 8);
    *(short8*)(xs + pos * 128 + ((ch * 16) ^ (((r + c) & 7) << 4))) = v;
  }
  __syncthreads();

  const unsigned* od = (const unsigned*)(offt + ((size_t)b * HW_ + p_img) * 72);
  const int thalf = lg >> 1;
  const int cofs0 = (lg & 1) * 8;

  // per-thread tap geometry (hoists t/3, t%3 out of the hot loop)
  float pyA[5], pxA[5];
  int liveA[5];
  #pragma unroll
  for (int s = 0; s < 5; ++s) {
    const int t = 2 * s + thalf;
    liveA[s] = (t < 9);
    const int tt = liveA[s] ? t : 0;
    pyA[s] = (float)(y - 1 + tt / 3);
    pxA[s] = (float)(x - 1 + tt % 3);
  }

  f32x4 acc[4];
  #pragma unroll
  for (int mf = 0; mf < 4; ++mf) acc[mf] = (f32x4){0.f, 0.f, 0.f, 0.f};

  #pragma unroll 1
  for (int g = 0; g < 4; ++g) {
    const int cofs = g * 16 + cofs0;
    const int chunkB = cofs * 2;
    #pragma unroll
    for (int s = 0; s < 5; ++s) {
      const int live = liveA[s];
      const int t = 2 * s + thalf;
      const unsigned dpair = od[g * 9 + (live ? t : 0)];
      const float dy = bf2f((unsigned short)(dpair & 0xffff));
      const float dx = bf2f((unsigned short)(dpair >> 16));
      const float sy = dy + pyA[s];
      const float sx = dx + pxA[s];
      const float fy = floorf(sy);
      const float fx = floorf(sx);
      const int y0 = (int)fy;
      const int x0 = (int)fx;
      const float ay = sy - fy;
      const float ax = sx - fx;
      const float by = 1.f - ay, bxx = 1.f - ax;
      float w00 = by * bxx, w01 = by * ax, w10 = ay * bxx, w11 = ay * ax;
      const int ry0 = y0 - ty + 4;       // tile-relative, UNCLAMPED
      const int rx0 = x0 - tx + 4;
      const bool inT = (!live) | (((unsigned)ry0 < 11u) & ((unsigned)rx0 < 23u));
      short8 q00, q01, q10, q11;
      if (__all((int)inT)) {
        // fast path: no clamps, no validity masks (zero-filled halo makes w*0 = 0)
        const int r0 = live ? ry0 : 0;
        const int c0 = live ? rx0 : 0;
        const int b00 = (r0 * 24 + c0) << 7;
        const int sw00 = b00 + (chunkB ^ (((r0 + c0) & 7) << 4));
        const int sw01 = b00 + 128 + (chunkB ^ (((r0 + c0 + 1) & 7) << 4));
        const int b10 = b00 + 24 * 128;
        const int sw10 = b10 + (chunkB ^ (((r0 + c0 + 1) & 7) << 4));
        const int sw11 = b10 + 128 + (chunkB ^ (((r0 + c0 + 2) & 7) << 4));
        q00 = *(const short8*)(xs + sw00);
        q01 = *(const short8*)(xs + sw01);
        q10 = *(const short8*)(xs + sw10);
        q11 = *(const short8*)(xs + sw11);
      } else {
        // cold path: full boundary handling + global gathers
        const bool vy0 = (y0 >= 0) & (y0 < HH);
        const bool vy1 = (y0 + 1 >= 0) & (y0 + 1 < HH);
        const bool vx0 = (x0 >= 0) & (x0 < WW);
        const bool vx1 = (x0 + 1 >= 0) & (x0 + 1 < WW);
        w00 = (vy0 & vx0) ? w00 : 0.f;
        w01 = (vy0 & vx1) ? w01 : 0.f;
        w10 = (vy1 & vx0) ? w10 : 0.f;
        w11 = (vy1 & vx1) ? w11 : 0.f;
        const int cy0 = min(max(y0, 0), HH - 1);
        const int cy1 = min(max(y0 + 1, 0), HH - 1);
        const int cx0 = min(max(x0, 0), WW - 1);
        const int cx1 = min(max(x0 + 1, 0), WW - 1);
        q00 = *(const short8*)(xb + (size_t)(cy0 * WW + cx0) * 64 + cofs);
        q01 = *(const short8*)(xb + (size_t)(cy0 * WW + cx1) * 64 + cofs);
        q10 = *(const short8*)(xb + (size_t)(cy1 * WW + cx0) * 64 + cofs);
        q11 = *(const short8*)(xb + (size_t)(cy1 * WW + cx1) * 64 + cofs);
      }
      short8 pf = (short8)0;
      if (live) {
        const unsigned* u00 = (const unsigned*)&q00;
        const unsigned* u01 = (const unsigned*)&q01;
        const unsigned* u10 = (const unsigned*)&q10;
        const unsigned* u11 = (const unsigned*)&q11;
        unsigned pr[4];
        #pragma unroll
        for (int i = 0; i < 4; ++i) {
          float2v f00, f01, f10, f11;
          f00.x = asf(u00[i] << 16); f00.y = asf(u00[i] & 0xffff0000u);
          f01.x = asf(u01[i] << 16); f01.y = asf(u01[i] & 0xffff0000u);
          f10.x = asf(u10[i] << 16); f10.y = asf(u10[i] & 0xffff0000u);
          f11.x = asf(u11[i] << 16); f11.y = asf(u11[i] & 0xffff0000u);
          const float2v s2 = f00 * w00 + f01 * w01 + f10 * w10 + f11 * w11;
          unsigned pk;
          asm("v_cvt_pk_bf16_f32 %0, %1, %2" : "=v"(pk) : "v"(s2.x), "v"(s2.y));
          pr[i] = pk;
        }
        pf = *(const short8*)pr;
      }
      #pragma unroll
      for (int mf = 0; mf < 4; ++mf) {
        const short8 wf = *(const short8*)(wdf + ((size_t)((g * 5 + s) * 4 + mf)) * 512 + l * 8);
        acc[mf] = __builtin_amdgcn_mfma_f32_16x16x32_bf16(wf, pf, acc[mf], 0, 0, 0);
      }
    }
  }

  float* ob = out + (size_t)b * 64 * HW_;
  #pragma unroll
  for (int mf = 0; mf < 4; ++mf) {
    #pragma unroll
    for (int r = 0; r < 4; ++r) {
      const int o = mf * 16 + lg * 4 + r;
      ob[(size_t)o * HW_ + p_img] = lrelu_f(acc[mf][r] + bias[o]);
    }
  }
}

extern "C" void kernel_launch(void* const* d_in, const int* in_sizes, int n_in,
                              void* d_out, int out_size, void* d_ws, size_t ws_size,
                              hipStream_t stream) {
  const float* nbr   = (const float*)d_in[0];
  const float* ref   = (const float*)d_in[1];
  const float* w_co1 = (const float*)d_in[2];
  const float* b_co1 = (const float*)d_in[3];
  const float* w_m1  = (const float*)d_in[4];
  const float* b_m1  = (const float*)d_in[5];
  const float* w_m2  = (const float*)d_in[6];
  const float* b_m2  = (const float*)d_in[7];
  const float* w_m3  = (const float*)d_in[8];
  const float* b_m3  = (const float*)d_in[9];
  const float* w_dcn = (const float*)d_in[10];
  const float* b_dcn = (const float*)d_in[11];
  float* out = (float*)d_out;

  char* ws = (char*)d_ws;
  unsigned short* xnb   = (unsigned short*)(ws);
  unsigned short* x1t   = (unsigned short*)(ws + 14680064);
  unsigned short* m1t   = (unsigned short*)(ws + 14680064);   // alias (after conv1)
  unsigned short* m2t   = (unsigned short*)(ws + 29360128);   // alias
  unsigned short* featt = (unsigned short*)(ws + 44040192);
  unsigned short* offt  = (unsigned short*)(ws + 44040192);   // alias (after m1)
  char* wbase = ws + 60555264;
  unsigned short* wf1  = (unsigned short*)(wbase);            // 147456
  unsigned short* wfm1 = (unsigned short*)(wbase + 147456);   // 73728
  unsigned short* wfm2 = (unsigned short*)(wbase + 221184);   // 73728
  unsigned short* wfm3 = (unsigned short*)(wbase + 294912);   // 92160
  unsigned short* wdf  = (unsigned short*)(wbase + 387072);   // 81920

  dim3 blk(256);
  prep_all<<<dim3(2708), blk, 0, stream>>>(nbr, ref, w_co1, w_m1, w_m2, w_m3, w_dcn,
                                           x1t, xnb, wf1, wfm1, wfm2, wfm3, wdf);

  conv_lds2<2, 4, 64, true ><<<dim3(112, 4), blk, 0, stream>>>(x1t,   wf1,  b_co1, featt, 64);
  conv_lds2<1, 4, 64, true ><<<dim3(112, 4), blk, 0, stream>>>(featt, wfm1, b_m1,  m1t,   64);
  conv_lds2<1, 4, 64, true ><<<dim3(112, 4), blk, 0, stream>>>(m1t,   wfm2, b_m2,  m2t,   64);
  conv_lds <1, 5, 72, false><<<dim3(224, 4), blk, 0, stream>>>(m2t,   wfm3, b_m3,  offt,  72);
  dcn_v7<<<dim3(448, 4), blk, 0, stream>>>(xnb, offt, wdf, b_dcn, out);
}